// Round 11
// baseline (519.617 us; speedup 1.0000x reference)
//
#include <hip/hip_runtime.h>

#define N_NODES 50000
#define N_EDGES 600000
#define N_PAD 50048        // N rounded up to 64 (mlp tiles)
#define IN_CH 64
#define HID 128
#define N_GRAPHS 64
#define SCAN_BLOCKS 196   // ceil(N_NODES/256)

typedef __attribute__((ext_vector_type(8))) short bf16x8;
typedef __attribute__((ext_vector_type(4))) float f32x4;

// ---- bf16 helpers (manual, RNE) ----
__device__ __forceinline__ float bf2f(unsigned short u) {
    union { unsigned int i; float f; } v; v.i = ((unsigned int)u) << 16; return v.f;
}
__device__ __forceinline__ unsigned short f2bf(float f) {
    union { float f; unsigned int i; } v; v.f = f;
    unsigned int u = v.i;
    return (unsigned short)((u + 0x7FFFu + ((u >> 16) & 1u)) >> 16);
}
__device__ __forceinline__ float rowval(float f) { return f; }
__device__ __forceinline__ float rowval(unsigned short u) { return bf2f(u); }

template <bool B> struct RowType { using T = float; };
template <> struct RowType<true> { using T = unsigned short; };

// ===========================================================================
// CSR build (R8/R9-proven): counting-sort edges by dst; edata = {src,a0,a1,a2}.
// ===========================================================================
__global__ void hist_kernel(const int* __restrict__ ei, int* __restrict__ deg) {
    int e = blockIdx.x * blockDim.x + threadIdx.x;
    if (e < N_EDGES) atomicAdd(&deg[ei[N_EDGES + e]], 1);
}

__device__ __forceinline__ int block_incl_scan256(int v, int* sm, int t) {
    int val = v;
    sm[t] = val; __syncthreads();
    #pragma unroll
    for (int off = 1; off < 256; off <<= 1) {
        int n = (t >= off) ? sm[t - off] : 0;
        __syncthreads();
        val += n; sm[t] = val; __syncthreads();
    }
    return val;
}

__global__ void scan1_kernel(const int* __restrict__ deg, int* __restrict__ partials) {
    __shared__ int sm[256];
    int t = threadIdx.x;
    int i = blockIdx.x * 256 + t;
    int v = (i < N_NODES) ? deg[i] : 0;
    sm[t] = v; __syncthreads();
    for (int off = 128; off > 0; off >>= 1) {
        if (t < off) sm[t] += sm[t + off];
        __syncthreads();
    }
    if (t == 0) partials[blockIdx.x] = sm[0];
}

__global__ void scan2_kernel(int* __restrict__ partials) {
    __shared__ int sm[256];
    int t = threadIdx.x;
    int v = (t < SCAN_BLOCKS) ? partials[t] : 0;
    int incl = block_incl_scan256(v, sm, t);
    if (t < SCAN_BLOCKS) partials[t] = incl - v;
}

__global__ void scan3_kernel(const int* __restrict__ deg,
                             const int* __restrict__ partials,
                             int* __restrict__ rowptr,
                             int* __restrict__ cursor) {
    __shared__ int sm[256];
    int t = threadIdx.x;
    int i = blockIdx.x * 256 + t;
    int v = (i < N_NODES) ? deg[i] : 0;
    int incl = block_incl_scan256(v, sm, t);
    int excl = incl - v + partials[blockIdx.x];
    if (i < N_NODES) { rowptr[i] = excl; cursor[i] = excl; }
    if (blockIdx.x == 0 && t == 0) rowptr[N_NODES] = N_EDGES;
}

__global__ void scatter_kernel(const int* __restrict__ ei,
                               const float* __restrict__ ea,
                               int* __restrict__ cursor,
                               int4* __restrict__ edata) {
    int e = blockIdx.x * blockDim.x + threadIdx.x;
    if (e < N_EDGES) {
        int dst = ei[N_EDGES + e];
        int pos = atomicAdd(&cursor[dst], 1);
        edata[pos] = make_int4(ei[e],
                               __float_as_int(ea[3 * e]),
                               __float_as_int(ea[3 * e + 1]),
                               __float_as_int(ea[3 * e + 2]));
    }
}

// transpose + bf16: wT[n*Kdim + k] = w[k*Ndim + n]  (R6/R10 correctness-proven)
__global__ void tw_kernel(const float* __restrict__ w, unsigned short* __restrict__ wT,
                          int Kdim, int Ndim) {
    int i = blockIdx.x * blockDim.x + threadIdx.x;
    if (i < Kdim * Ndim) {
        int k = i / Ndim, n = i % Ndim;
        wT[n * Kdim + k] = f2bf(w[k * Ndim + n]);
    }
}

// ===========================================================================
// Gather kernel — R9's proven gather phase, STANDALONE (R6+R10 lesson: an
// MFMA section in the same kernel wrecks the gather's load batching:
// VALUBusy 47%->8%). Writes aggregated rows to global as bf16. No LDS.
//   sg[n] = x[n] + sum_{e: dst(e)=n} relu(x[src(e)] + ea[e]@elw + elb)
// ===========================================================================
template <int K, bool XBF>
__global__ void gather_kernel(const void* __restrict__ xinv,
                              const int4* __restrict__ edata,
                              const int* __restrict__ rowptr,
                              const float* __restrict__ elw,  // [3, K]
                              const float* __restrict__ elb,  // [K]
                              unsigned short* __restrict__ sg) {  // bf16 [N_PAD, K]
    using RowT = typename RowType<XBF>::T;
    const RowT* __restrict__ xin = (const RowT*)xinv;
    constexpr int NPB = 8;
    const int node0 = blockIdx.x * NPB;
    const int t = threadIdx.x;  // 0..127

    const int c = (K == 128) ? t : (t & 63);
    const int half = (K == 128) ? 0 : (t >> 6);
    const int istep = (K == 128) ? 1 : 2;
    const float w0 = elw[c], w1 = elw[K + c], w2 = elw[2 * K + c], eb = elb[c];

    auto term = [&](int4 e, RowT row) -> float {
        float ev = __int_as_float(e.y) * w0 + __int_as_float(e.z) * w1 +
                   __int_as_float(e.w) * w2 + eb;
        float m = rowval(row) + ev;
        return m > 0.f ? m : 0.f;
    };

    for (int i = 0; i < NPB; i += istep) {
        int node = node0 + i + half;
        float acc = rowval(xin[(size_t)node * K + c]);
        int jb = rowptr[node], je = rowptr[node + 1];
        int j = jb;
        for (; j + 8 <= je; j += 8) {
            int4 e0 = edata[j],     e1 = edata[j + 1], e2 = edata[j + 2], e3 = edata[j + 3];
            int4 e4 = edata[j + 4], e5 = edata[j + 5], e6 = edata[j + 6], e7 = edata[j + 7];
            RowT r0 = xin[(size_t)e0.x * K + c];
            RowT r1 = xin[(size_t)e1.x * K + c];
            RowT r2 = xin[(size_t)e2.x * K + c];
            RowT r3 = xin[(size_t)e3.x * K + c];
            RowT r4 = xin[(size_t)e4.x * K + c];
            RowT r5 = xin[(size_t)e5.x * K + c];
            RowT r6 = xin[(size_t)e6.x * K + c];
            RowT r7 = xin[(size_t)e7.x * K + c];
            acc += term(e0, r0) + term(e1, r1) + term(e2, r2) + term(e3, r3)
                 + term(e4, r4) + term(e5, r5) + term(e6, r6) + term(e7, r7);
        }
        for (; j + 4 <= je; j += 4) {
            int4 e0 = edata[j], e1 = edata[j + 1], e2 = edata[j + 2], e3 = edata[j + 3];
            RowT r0 = xin[(size_t)e0.x * K + c];
            RowT r1 = xin[(size_t)e1.x * K + c];
            RowT r2 = xin[(size_t)e2.x * K + c];
            RowT r3 = xin[(size_t)e3.x * K + c];
            acc += term(e0, r0) + term(e1, r1) + term(e2, r2) + term(e3, r3);
        }
        for (; j < je; j++) {
            int4 e0 = edata[j];
            acc += term(e0, xin[(size_t)e0.x * K + c]);
        }
        sg[(size_t)node * K + c] = f2bf(acc);
    }
}

// ===========================================================================
// Standalone MFMA MLP (tall-skinny GEMM), R6/R10-proven fragment layout:
//   out = relu( relu(sg @ wa + ba) @ wb + bb )
// 256 threads = 4 waves; each wave owns 16 rows (nodes) and computes all 128
// output cols (8 tiles of 16). Per-wave LDS buffer for the A-layout
// transpose between layers (D layout: col=lane&15, row=quad*4+reg).
// Rows >= N_NODES are garbage (padded input); MFMA rows are independent so
// they never contaminate valid rows; epilogue guards node < N_NODES.
// ===========================================================================
template <int K, bool POOL>
__global__ __launch_bounds__(256)
void mlp_mfma_kernel(const unsigned short* __restrict__ sg,   // bf16 [N_PAD, K]
                     const unsigned short* __restrict__ waT,  // bf16 [HID, K]
                     const float* __restrict__ ba,
                     const unsigned short* __restrict__ wbT,  // bf16 [HID, HID]
                     const float* __restrict__ bb,
                     void* __restrict__ outv,                 // bf16 h or f32 psum
                     const int* __restrict__ batch) {
    constexpr int HSTR = 136;  // shorts; 272 B row stride (16B multiple)
    __shared__ __align__(16) unsigned short sHid[4][16 * HSTR];
    const int t = threadIdx.x;
    const int w = t >> 6, l = t & 63;
    const int i16 = l & 15, q = l >> 4;
    const int row0 = blockIdx.x * 64 + w * 16;   // this wave's 16 rows

    // ---- layer A: [16 x K] @ waT -> relu -> own LDS buffer ----
    bf16x8 aA[K / 32];
    #pragma unroll
    for (int s = 0; s < K / 32; s++)
        aA[s] = *(const bf16x8*)&sg[(size_t)(row0 + i16) * K + s * 32 + q * 8];
    unsigned short* myHid = sHid[w];
    #pragma unroll
    for (int ct = 0; ct < 8; ct++) {
        int col = ct * 16 + i16;
        float bv = ba[col];
        f32x4 acc = (f32x4){bv, bv, bv, bv};
        #pragma unroll
        for (int s = 0; s < K / 32; s++) {
            bf16x8 b = *(const bf16x8*)&waT[(size_t)col * K + s * 32 + q * 8];
            acc = __builtin_amdgcn_mfma_f32_16x16x32_bf16(aA[s], b, acc, 0, 0, 0);
        }
        #pragma unroll
        for (int r = 0; r < 4; r++) {
            float v = acc[r] > 0.f ? acc[r] : 0.f;
            myHid[(q * 4 + r) * HSTR + col] = f2bf(v);
        }
    }
    __syncthreads();  // cheap; guarantees LDS write->read ordering

    // ---- layer B: [16 x 128] @ wbT -> relu -> out ----
    bf16x8 aB[4];
    #pragma unroll
    for (int s = 0; s < 4; s++)
        aB[s] = *(const bf16x8*)&myHid[i16 * HSTR + s * 32 + q * 8];
    #pragma unroll
    for (int ct = 0; ct < 8; ct++) {
        int col = ct * 16 + i16;
        float bv = bb[col];
        f32x4 acc = (f32x4){bv, bv, bv, bv};
        #pragma unroll
        for (int s = 0; s < 4; s++) {
            bf16x8 b = *(const bf16x8*)&wbT[(size_t)col * HID + s * 32 + q * 8];
            acc = __builtin_amdgcn_mfma_f32_16x16x32_bf16(aB[s], b, acc, 0, 0, 0);
        }
        #pragma unroll
        for (int r = 0; r < 4; r++) {
            int node = row0 + q * 4 + r;
            if (node < N_NODES) {
                float v = acc[r] > 0.f ? acc[r] : 0.f;
                if (POOL) {
                    atomicAdd(&((float*)outv)[batch[node] * HID + col], v);
                } else {
                    ((unsigned short*)outv)[(size_t)node * HID + col] = f2bf(v);
                }
            }
        }
    }
}

// ---------------------------------------------------------------------------
// Pool mean: batch is SORTED -> count[g] by binary search (wave-uniform).
// ---------------------------------------------------------------------------
__global__ void pool_div_kernel(const float* __restrict__ sums,
                                const int* __restrict__ batch,
                                float* __restrict__ out) {
    int i = blockIdx.x * blockDim.x + threadIdx.x;
    if (i >= N_GRAPHS * HID) return;
    int g = i / HID;
    int lo = 0, hi = N_NODES;
    while (lo < hi) { int mid = (lo + hi) >> 1; if (batch[mid] < g) lo = mid + 1; else hi = mid; }
    int start = lo;
    lo = 0; hi = N_NODES;
    while (lo < hi) { int mid = (lo + hi) >> 1; if (batch[mid] <= g) lo = mid + 1; else hi = mid; }
    float c = (float)(lo - start);
    out[i] = sums[i] / (c > 1.0f ? c : 1.0f);
}

extern "C" void kernel_launch(void* const* d_in, const int* in_sizes, int n_in,
                              void* d_out, int out_size, void* d_ws, size_t ws_size,
                              hipStream_t stream) {
    const float* x    = (const float*)d_in[0];
    const int*   ei   = (const int*)d_in[1];
    const float* ea   = (const float*)d_in[2];
    const int*   batch= (const int*)d_in[3];
    const float* el1w = (const float*)d_in[4];
    const float* el1b = (const float*)d_in[5];
    const float* w1a  = (const float*)d_in[6];
    const float* b1a  = (const float*)d_in[7];
    const float* w1b  = (const float*)d_in[8];
    const float* b1b  = (const float*)d_in[9];
    const float* el2w = (const float*)d_in[10];
    const float* el2b = (const float*)d_in[11];
    const float* w2a  = (const float*)d_in[12];
    const float* b2a  = (const float*)d_in[13];
    const float* w2b  = (const float*)d_in[14];
    const float* b2b  = (const float*)d_in[15];
    float* out = (float*)d_out;

    // workspace layout (16B-aligned sections)
    int4*  edata    = (int4*)d_ws;                      // [E] {src,a0,a1,a2}   9.6 MB
    float* psum     = (float*)(edata + N_EDGES);        // [G*HID] 8192 f32
    int*   deg      = (int*)(psum + N_GRAPHS * HID);    // [N]
    int*   cursor   = deg + N_NODES;                    // [N]
    int*   rowptr   = cursor + N_NODES;                 // [N+1]
    int*   partials = rowptr + N_NODES + 1;             // [256]
    // ints so far: 8192+50000+50000+50001+256 = 158449; pad to 158452 (16B mult)
    unsigned short* hbf  = (unsigned short*)((char*)psum + (size_t)158452 * 4);  // bf16 [N,HID]
    unsigned short* sgbuf= hbf + (size_t)N_NODES * HID;  // bf16 [N_PAD, 128] (layer1 uses stride 64)
    unsigned short* waT1 = sgbuf + (size_t)N_PAD * HID;  // bf16 [128, 64]
    unsigned short* wbT1 = waT1 + HID * IN_CH;           // bf16 [128, 128]
    unsigned short* waT2 = wbT1 + HID * HID;             // bf16 [128, 128]
    unsigned short* wbT2 = waT2 + HID * HID;             // bf16 [128, 128]

    // ---- prep: CSR build (parallel scan) + weight transpose ----
    hipMemsetAsync(deg, 0, N_NODES * sizeof(int), stream);
    hist_kernel<<<(N_EDGES + 255) / 256, 256, 0, stream>>>(ei, deg);
    tw_kernel<<<(IN_CH * HID + 255) / 256, 256, 0, stream>>>(w1a, waT1, IN_CH, HID);
    tw_kernel<<<(HID * HID + 255) / 256, 256, 0, stream>>>(w1b, wbT1, HID, HID);
    tw_kernel<<<(HID * HID + 255) / 256, 256, 0, stream>>>(w2a, waT2, HID, HID);
    tw_kernel<<<(HID * HID + 255) / 256, 256, 0, stream>>>(w2b, wbT2, HID, HID);
    scan1_kernel<<<SCAN_BLOCKS, 256, 0, stream>>>(deg, partials);
    scan2_kernel<<<1, 256, 0, stream>>>(partials);
    scan3_kernel<<<SCAN_BLOCKS, 256, 0, stream>>>(deg, partials, rowptr, cursor);
    scatter_kernel<<<(N_EDGES + 255) / 256, 256, 0, stream>>>(ei, ea, cursor, edata);

    // ---- layer 1: f32 gather -> sg (bf16) ; MFMA MLP -> hbf (bf16) ----
    gather_kernel<IN_CH, false><<<N_NODES / 8, 128, 0, stream>>>(
        x, edata, rowptr, el1w, el1b, sgbuf);
    mlp_mfma_kernel<IN_CH, false><<<N_PAD / 64, 256, 0, stream>>>(
        sgbuf, waT1, b1a, wbT1, b1b, hbf, nullptr);

    // ---- layer 2: bf16 gather -> sg ; MFMA MLP + pool atomics ----
    hipMemsetAsync(psum, 0, N_GRAPHS * HID * sizeof(float), stream);
    gather_kernel<HID, true><<<N_NODES / 8, 128, 0, stream>>>(
        hbf, edata, rowptr, el2w, el2b, sgbuf);
    mlp_mfma_kernel<HID, true><<<N_PAD / 64, 256, 0, stream>>>(
        sgbuf, waT2, b2a, wbT2, b2b, psum, batch);

    // ---- mean (count via binary search on sorted batch) ----
    pool_div_kernel<<<(N_GRAPHS * HID + 255) / 256, 256, 0, stream>>>(psum, batch, out);
}

// Round 12
// 321.043 us; speedup vs baseline: 1.6185x; 1.6185x over previous
//
#include <hip/hip_runtime.h>

#define N_NODES 50000
#define N_EDGES 600000
#define N_PAD 50048        // N rounded up to 64 (mlp tiles)
#define IN_CH 64
#define HID 128
#define N_GRAPHS 64
#define SCAN_BLOCKS 196   // ceil(N_NODES/256)

typedef __attribute__((ext_vector_type(8))) short bf16x8;
typedef __attribute__((ext_vector_type(4))) float f32x4;

// ---- bf16 helpers (manual, RNE) ----
__device__ __forceinline__ float bf2f(unsigned short u) {
    union { unsigned int i; float f; } v; v.i = ((unsigned int)u) << 16; return v.f;
}
__device__ __forceinline__ unsigned short f2bf(float f) {
    union { float f; unsigned int i; } v; v.f = f;
    unsigned int u = v.i;
    return (unsigned short)((u + 0x7FFFu + ((u >> 16) & 1u)) >> 16);
}
__device__ __forceinline__ float rowval(float f) { return f; }
__device__ __forceinline__ float rowval(unsigned short u) { return bf2f(u); }

template <bool B> struct RowType { using T = float; };
template <> struct RowType<true> { using T = unsigned short; };

// ===========================================================================
// CSR build (R8/R9-proven): counting-sort edges by dst; edata = {src,a0,a1,a2}.
// ===========================================================================
__global__ void hist_kernel(const int* __restrict__ ei, int* __restrict__ deg) {
    int e = blockIdx.x * blockDim.x + threadIdx.x;
    if (e < N_EDGES) atomicAdd(&deg[ei[N_EDGES + e]], 1);
}

__device__ __forceinline__ int block_incl_scan256(int v, int* sm, int t) {
    int val = v;
    sm[t] = val; __syncthreads();
    #pragma unroll
    for (int off = 1; off < 256; off <<= 1) {
        int n = (t >= off) ? sm[t - off] : 0;
        __syncthreads();
        val += n; sm[t] = val; __syncthreads();
    }
    return val;
}

__global__ void scan1_kernel(const int* __restrict__ deg, int* __restrict__ partials) {
    __shared__ int sm[256];
    int t = threadIdx.x;
    int i = blockIdx.x * 256 + t;
    int v = (i < N_NODES) ? deg[i] : 0;
    sm[t] = v; __syncthreads();
    for (int off = 128; off > 0; off >>= 1) {
        if (t < off) sm[t] += sm[t + off];
        __syncthreads();
    }
    if (t == 0) partials[blockIdx.x] = sm[0];
}

__global__ void scan2_kernel(int* __restrict__ partials) {
    __shared__ int sm[256];
    int t = threadIdx.x;
    int v = (t < SCAN_BLOCKS) ? partials[t] : 0;
    int incl = block_incl_scan256(v, sm, t);
    if (t < SCAN_BLOCKS) partials[t] = incl - v;
}

__global__ void scan3_kernel(const int* __restrict__ deg,
                             const int* __restrict__ partials,
                             int* __restrict__ rowptr,
                             int* __restrict__ cursor) {
    __shared__ int sm[256];
    int t = threadIdx.x;
    int i = blockIdx.x * 256 + t;
    int v = (i < N_NODES) ? deg[i] : 0;
    int incl = block_incl_scan256(v, sm, t);
    int excl = incl - v + partials[blockIdx.x];
    if (i < N_NODES) { rowptr[i] = excl; cursor[i] = excl; }
    if (blockIdx.x == 0 && t == 0) rowptr[N_NODES] = N_EDGES;
}

__global__ void scatter_kernel(const int* __restrict__ ei,
                               const float* __restrict__ ea,
                               int* __restrict__ cursor,
                               int4* __restrict__ edata) {
    int e = blockIdx.x * blockDim.x + threadIdx.x;
    if (e < N_EDGES) {
        int dst = ei[N_EDGES + e];
        int pos = atomicAdd(&cursor[dst], 1);
        edata[pos] = make_int4(ei[e],
                               __float_as_int(ea[3 * e]),
                               __float_as_int(ea[3 * e + 1]),
                               __float_as_int(ea[3 * e + 2]));
    }
}

// transpose + bf16: wT[n*Kdim + k] = w[k*Ndim + n]  (R6/R10 correctness-proven)
__global__ void tw_kernel(const float* __restrict__ w, unsigned short* __restrict__ wT,
                          int Kdim, int Ndim) {
    int i = blockIdx.x * blockDim.x + threadIdx.x;
    if (i < Kdim * Ndim) {
        int k = i / Ndim, n = i % Ndim;
        wT[n * Kdim + k] = f2bf(w[k * Ndim + n]);
    }
}

// ===========================================================================
// Gather kernel — R9's proven gather phase, STANDALONE (R6+R10 lesson: an
// MFMA section in the same kernel wrecks the gather's load batching).
// Writes aggregated rows to global as bf16. No LDS. R11-identical.
// ===========================================================================
template <int K, bool XBF>
__global__ void gather_kernel(const void* __restrict__ xinv,
                              const int4* __restrict__ edata,
                              const int* __restrict__ rowptr,
                              const float* __restrict__ elw,  // [3, K]
                              const float* __restrict__ elb,  // [K]
                              unsigned short* __restrict__ sg) {  // bf16 [N_PAD, K]
    using RowT = typename RowType<XBF>::T;
    const RowT* __restrict__ xin = (const RowT*)xinv;
    constexpr int NPB = 8;
    const int node0 = blockIdx.x * NPB;
    const int t = threadIdx.x;  // 0..127

    const int c = (K == 128) ? t : (t & 63);
    const int half = (K == 128) ? 0 : (t >> 6);
    const int istep = (K == 128) ? 1 : 2;
    const float w0 = elw[c], w1 = elw[K + c], w2 = elw[2 * K + c], eb = elb[c];

    auto term = [&](int4 e, RowT row) -> float {
        float ev = __int_as_float(e.y) * w0 + __int_as_float(e.z) * w1 +
                   __int_as_float(e.w) * w2 + eb;
        float m = rowval(row) + ev;
        return m > 0.f ? m : 0.f;
    };

    for (int i = 0; i < NPB; i += istep) {
        int node = node0 + i + half;
        float acc = rowval(xin[(size_t)node * K + c]);
        int jb = rowptr[node], je = rowptr[node + 1];
        int j = jb;
        for (; j + 8 <= je; j += 8) {
            int4 e0 = edata[j],     e1 = edata[j + 1], e2 = edata[j + 2], e3 = edata[j + 3];
            int4 e4 = edata[j + 4], e5 = edata[j + 5], e6 = edata[j + 6], e7 = edata[j + 7];
            RowT r0 = xin[(size_t)e0.x * K + c];
            RowT r1 = xin[(size_t)e1.x * K + c];
            RowT r2 = xin[(size_t)e2.x * K + c];
            RowT r3 = xin[(size_t)e3.x * K + c];
            RowT r4 = xin[(size_t)e4.x * K + c];
            RowT r5 = xin[(size_t)e5.x * K + c];
            RowT r6 = xin[(size_t)e6.x * K + c];
            RowT r7 = xin[(size_t)e7.x * K + c];
            acc += term(e0, r0) + term(e1, r1) + term(e2, r2) + term(e3, r3)
                 + term(e4, r4) + term(e5, r5) + term(e6, r6) + term(e7, r7);
        }
        for (; j + 4 <= je; j += 4) {
            int4 e0 = edata[j], e1 = edata[j + 1], e2 = edata[j + 2], e3 = edata[j + 3];
            RowT r0 = xin[(size_t)e0.x * K + c];
            RowT r1 = xin[(size_t)e1.x * K + c];
            RowT r2 = xin[(size_t)e2.x * K + c];
            RowT r3 = xin[(size_t)e3.x * K + c];
            acc += term(e0, r0) + term(e1, r1) + term(e2, r2) + term(e3, r3);
        }
        for (; j < je; j++) {
            int4 e0 = edata[j];
            acc += term(e0, xin[(size_t)e0.x * K + c]);
        }
        sg[(size_t)node * K + c] = f2bf(acc);
    }
}

// ===========================================================================
// Standalone MFMA MLP. MFMA body = R11 (proven). NEW epilogue (R11 lesson:
// raw C-fragment atomics = 6.4M f32 atomics w/ 4-way intra-wave same-address
// conflicts -> 245us idle kernel, WRITE 43.7MB write-through):
//   C fragments -> LDS f32 sOut[64][132] -> either
//     POOL:  per-column segmented reduction over the block's 64 sorted rows,
//            then 1-3 atomics/column (~200K total, no intra-wave aliasing)
//     else:  coalesced packed bf16 row stores (16B/lane)
// ===========================================================================
template <int K, bool POOL>
__global__ __launch_bounds__(256)
void mlp_mfma_kernel(const unsigned short* __restrict__ sg,   // bf16 [N_PAD, K]
                     const unsigned short* __restrict__ waT,  // bf16 [HID, K]
                     const float* __restrict__ ba,
                     const unsigned short* __restrict__ wbT,  // bf16 [HID, HID]
                     const float* __restrict__ bb,
                     void* __restrict__ outv,                 // bf16 h or f32 psum
                     const int* __restrict__ batch) {
    constexpr int HSTR = 136;      // shorts
    constexpr int OSTR = HID + 4;  // f32
    __shared__ __align__(16) unsigned short sHid[4][16 * HSTR];  // 17.4 KB
    __shared__ __align__(16) float sOut[64 * OSTR];              // 33.8 KB
    const int t = threadIdx.x;
    const int w = t >> 6, l = t & 63;
    const int i16 = l & 15, q = l >> 4;
    const int blk0 = blockIdx.x * 64;
    const int row0 = blk0 + w * 16;   // this wave's 16 rows

    // ---- layer A: [16 x K] @ waT -> relu -> own LDS buffer ----
    bf16x8 aA[K / 32];
    #pragma unroll
    for (int s = 0; s < K / 32; s++)
        aA[s] = *(const bf16x8*)&sg[(size_t)(row0 + i16) * K + s * 32 + q * 8];
    unsigned short* myHid = sHid[w];
    #pragma unroll
    for (int ct = 0; ct < 8; ct++) {
        int col = ct * 16 + i16;
        float bv = ba[col];
        f32x4 acc = (f32x4){bv, bv, bv, bv};
        #pragma unroll
        for (int s = 0; s < K / 32; s++) {
            bf16x8 b = *(const bf16x8*)&waT[(size_t)col * K + s * 32 + q * 8];
            acc = __builtin_amdgcn_mfma_f32_16x16x32_bf16(aA[s], b, acc, 0, 0, 0);
        }
        #pragma unroll
        for (int r = 0; r < 4; r++) {
            float v = acc[r] > 0.f ? acc[r] : 0.f;
            myHid[(q * 4 + r) * HSTR + col] = f2bf(v);
        }
    }
    __syncthreads();

    // ---- layer B: [16 x 128] @ wbT -> relu -> sOut (f32 LDS) ----
    bf16x8 aB[4];
    #pragma unroll
    for (int s = 0; s < 4; s++)
        aB[s] = *(const bf16x8*)&myHid[i16 * HSTR + s * 32 + q * 8];
    #pragma unroll
    for (int ct = 0; ct < 8; ct++) {
        int col = ct * 16 + i16;
        float bv = bb[col];
        f32x4 acc = (f32x4){bv, bv, bv, bv};
        #pragma unroll
        for (int s = 0; s < 4; s++) {
            bf16x8 b = *(const bf16x8*)&wbT[(size_t)col * HID + s * 32 + q * 8];
            acc = __builtin_amdgcn_mfma_f32_16x16x32_bf16(aB[s], b, acc, 0, 0, 0);
        }
        #pragma unroll
        for (int r = 0; r < 4; r++) {
            float v = acc[r] > 0.f ? acc[r] : 0.f;
            sOut[(w * 16 + q * 4 + r) * OSTR + col] = v;
        }
    }
    __syncthreads();

    // ---- epilogue ----
    if (POOL) {
        if (t < HID) {
            float* psum = (float*)outv;
            float acc = 0.f;
            int curg = batch[blk0];
            for (int row = 0; row < 64; row++) {
                int node = blk0 + row;
                if (node >= N_NODES) break;
                int g = batch[node];
                if (g != curg) {
                    atomicAdd(&psum[curg * HID + t], acc);
                    acc = 0.f; curg = g;
                }
                acc += sOut[row * OSTR + t];
            }
            atomicAdd(&psum[curg * HID + t], acc);
        }
    } else {
        unsigned short* hout = (unsigned short*)outv;
        for (int idx = t; idx < 64 * 16; idx += 256) {
            int row = idx >> 4, ch = idx & 15;   // ch = 16B chunk (8 bf16)
            int node = blk0 + row;
            if (node < N_NODES) {
                float4 f0 = *(const float4*)&sOut[row * OSTR + ch * 8];
                float4 f1 = *(const float4*)&sOut[row * OSTR + ch * 8 + 4];
                uint4 u;
                u.x = (unsigned)f2bf(f0.x) | ((unsigned)f2bf(f0.y) << 16);
                u.y = (unsigned)f2bf(f0.z) | ((unsigned)f2bf(f0.w) << 16);
                u.z = (unsigned)f2bf(f1.x) | ((unsigned)f2bf(f1.y) << 16);
                u.w = (unsigned)f2bf(f1.z) | ((unsigned)f2bf(f1.w) << 16);
                *(uint4*)&hout[(size_t)node * HID + ch * 8] = u;
            }
        }
    }
}

// ---------------------------------------------------------------------------
// Pool mean: batch is SORTED -> count[g] by binary search (wave-uniform).
// ---------------------------------------------------------------------------
__global__ void pool_div_kernel(const float* __restrict__ sums,
                                const int* __restrict__ batch,
                                float* __restrict__ out) {
    int i = blockIdx.x * blockDim.x + threadIdx.x;
    if (i >= N_GRAPHS * HID) return;
    int g = i / HID;
    int lo = 0, hi = N_NODES;
    while (lo < hi) { int mid = (lo + hi) >> 1; if (batch[mid] < g) lo = mid + 1; else hi = mid; }
    int start = lo;
    lo = 0; hi = N_NODES;
    while (lo < hi) { int mid = (lo + hi) >> 1; if (batch[mid] <= g) lo = mid + 1; else hi = mid; }
    float c = (float)(lo - start);
    out[i] = sums[i] / (c > 1.0f ? c : 1.0f);
}

extern "C" void kernel_launch(void* const* d_in, const int* in_sizes, int n_in,
                              void* d_out, int out_size, void* d_ws, size_t ws_size,
                              hipStream_t stream) {
    const float* x    = (const float*)d_in[0];
    const int*   ei   = (const int*)d_in[1];
    const float* ea   = (const float*)d_in[2];
    const int*   batch= (const int*)d_in[3];
    const float* el1w = (const float*)d_in[4];
    const float* el1b = (const float*)d_in[5];
    const float* w1a  = (const float*)d_in[6];
    const float* b1a  = (const float*)d_in[7];
    const float* w1b  = (const float*)d_in[8];
    const float* b1b  = (const float*)d_in[9];
    const float* el2w = (const float*)d_in[10];
    const float* el2b = (const float*)d_in[11];
    const float* w2a  = (const float*)d_in[12];
    const float* b2a  = (const float*)d_in[13];
    const float* w2b  = (const float*)d_in[14];
    const float* b2b  = (const float*)d_in[15];
    float* out = (float*)d_out;

    // workspace layout (16B-aligned sections)
    int4*  edata    = (int4*)d_ws;                      // [E] {src,a0,a1,a2}   9.6 MB
    float* psum     = (float*)(edata + N_EDGES);        // [G*HID] 8192 f32
    int*   deg      = (int*)(psum + N_GRAPHS * HID);    // [N]
    int*   cursor   = deg + N_NODES;                    // [N]
    int*   rowptr   = cursor + N_NODES;                 // [N+1]
    int*   partials = rowptr + N_NODES + 1;             // [256]
    // ints so far: 8192+50000+50000+50001+256 = 158449; pad to 158452 (16B mult)
    unsigned short* hbf  = (unsigned short*)((char*)psum + (size_t)158452 * 4);  // bf16 [N,HID]
    unsigned short* sgbuf= hbf + (size_t)N_NODES * HID;  // bf16 [N_PAD, 128] (layer1 uses stride 64)
    unsigned short* waT1 = sgbuf + (size_t)N_PAD * HID;  // bf16 [128, 64]
    unsigned short* wbT1 = waT1 + HID * IN_CH;           // bf16 [128, 128]
    unsigned short* waT2 = wbT1 + HID * HID;             // bf16 [128, 128]
    unsigned short* wbT2 = waT2 + HID * HID;             // bf16 [128, 128]

    // ---- prep: CSR build (parallel scan) + weight transpose ----
    hipMemsetAsync(deg, 0, N_NODES * sizeof(int), stream);
    hist_kernel<<<(N_EDGES + 255) / 256, 256, 0, stream>>>(ei, deg);
    tw_kernel<<<(IN_CH * HID + 255) / 256, 256, 0, stream>>>(w1a, waT1, IN_CH, HID);
    tw_kernel<<<(HID * HID + 255) / 256, 256, 0, stream>>>(w1b, wbT1, HID, HID);
    tw_kernel<<<(HID * HID + 255) / 256, 256, 0, stream>>>(w2a, waT2, HID, HID);
    tw_kernel<<<(HID * HID + 255) / 256, 256, 0, stream>>>(w2b, wbT2, HID, HID);
    scan1_kernel<<<SCAN_BLOCKS, 256, 0, stream>>>(deg, partials);
    scan2_kernel<<<1, 256, 0, stream>>>(partials);
    scan3_kernel<<<SCAN_BLOCKS, 256, 0, stream>>>(deg, partials, rowptr, cursor);
    scatter_kernel<<<(N_EDGES + 255) / 256, 256, 0, stream>>>(ei, ea, cursor, edata);

    // ---- layer 1: f32 gather -> sg (bf16) ; MFMA MLP -> hbf (bf16) ----
    gather_kernel<IN_CH, false><<<N_NODES / 8, 128, 0, stream>>>(
        x, edata, rowptr, el1w, el1b, sgbuf);
    mlp_mfma_kernel<IN_CH, false><<<N_PAD / 64, 256, 0, stream>>>(
        sgbuf, waT1, b1a, wbT1, b1b, hbf, nullptr);

    // ---- layer 2: bf16 gather -> sg ; MFMA MLP + LDS-reduced pool ----
    hipMemsetAsync(psum, 0, N_GRAPHS * HID * sizeof(float), stream);
    gather_kernel<HID, true><<<N_NODES / 8, 128, 0, stream>>>(
        hbf, edata, rowptr, el2w, el2b, sgbuf);
    mlp_mfma_kernel<HID, true><<<N_PAD / 64, 256, 0, stream>>>(
        sgbuf, waT2, b2a, wbT2, b2b, psum, batch);

    // ---- mean (count via binary search on sorted batch) ----
    pool_div_kernel<<<(N_GRAPHS * HID + 255) / 256, 256, 0, stream>>>(psum, batch, out);
}

// Round 13
// 308.306 us; speedup vs baseline: 1.6854x; 1.0413x over previous
//
#include <hip/hip_runtime.h>

#define N_NODES 50000
#define N_EDGES 600000
#define N_PAD 50048        // N rounded up to 64 (mlp tiles)
#define IN_CH 64
#define HID 128
#define N_GRAPHS 64
#define SCAN_BLOCKS 196   // ceil(N_NODES/256)

typedef __attribute__((ext_vector_type(8))) short bf16x8;
typedef __attribute__((ext_vector_type(4))) float f32x4;

// ---- bf16 helpers (manual, RNE) ----
__device__ __forceinline__ float bf2f(unsigned short u) {
    union { unsigned int i; float f; } v; v.i = ((unsigned int)u) << 16; return v.f;
}
__device__ __forceinline__ unsigned short f2bf(float f) {
    union { float f; unsigned int i; } v; v.f = f;
    unsigned int u = v.i;
    return (unsigned short)((u + 0x7FFFu + ((u >> 16) & 1u)) >> 16);
}

// ===========================================================================
// prep kernel: zero deg + zero psum + all 4 weight transposes in ONE dispatch
// (R12 lesson: 16 serial dispatches; launch slots are a visible cost).
// ===========================================================================
__global__ void prep_kernel(const float* __restrict__ w1a, const float* __restrict__ w1b,
                            const float* __restrict__ w2a, const float* __restrict__ w2b,
                            unsigned short* __restrict__ waT1, unsigned short* __restrict__ wbT1,
                            unsigned short* __restrict__ waT2, unsigned short* __restrict__ wbT2,
                            int* __restrict__ deg, float* __restrict__ psum) {
    int i = blockIdx.x * blockDim.x + threadIdx.x;
    if (i < N_NODES) deg[i] = 0;
    if (i < N_GRAPHS * HID) psum[i] = 0.f;
    if (i < IN_CH * HID) {               // w1a is [64,128]
        int k = i / HID, n = i % HID;
        waT1[n * IN_CH + k] = f2bf(w1a[i]);
    }
    if (i < HID * HID) {                 // the three [128,128] weights
        int k = i / HID, n = i % HID;
        wbT1[n * HID + k] = f2bf(w1b[i]);
        waT2[n * HID + k] = f2bf(w2a[i]);
        wbT2[n * HID + k] = f2bf(w2b[i]);
    }
}

// ===========================================================================
// CSR build (R8/R9-proven): counting-sort edges by dst; edata = {src,a0,a1,a2}.
// ===========================================================================
__global__ void hist_kernel(const int* __restrict__ ei, int* __restrict__ deg) {
    int e = blockIdx.x * blockDim.x + threadIdx.x;
    if (e < N_EDGES) atomicAdd(&deg[ei[N_EDGES + e]], 1);
}

__device__ __forceinline__ int block_incl_scan256(int v, int* sm, int t) {
    int val = v;
    sm[t] = val; __syncthreads();
    #pragma unroll
    for (int off = 1; off < 256; off <<= 1) {
        int n = (t >= off) ? sm[t - off] : 0;
        __syncthreads();
        val += n; sm[t] = val; __syncthreads();
    }
    return val;
}

__global__ void scan1_kernel(const int* __restrict__ deg, int* __restrict__ partials) {
    __shared__ int sm[256];
    int t = threadIdx.x;
    int i = blockIdx.x * 256 + t;
    int v = (i < N_NODES) ? deg[i] : 0;
    sm[t] = v; __syncthreads();
    for (int off = 128; off > 0; off >>= 1) {
        if (t < off) sm[t] += sm[t + off];
        __syncthreads();
    }
    if (t == 0) partials[blockIdx.x] = sm[0];
}

__global__ void scan2_kernel(int* __restrict__ partials) {
    __shared__ int sm[256];
    int t = threadIdx.x;
    int v = (t < SCAN_BLOCKS) ? partials[t] : 0;
    int incl = block_incl_scan256(v, sm, t);
    if (t < SCAN_BLOCKS) partials[t] = incl - v;
}

__global__ void scan3_kernel(const int* __restrict__ deg,
                             const int* __restrict__ partials,
                             int* __restrict__ rowptr,
                             int* __restrict__ cursor) {
    __shared__ int sm[256];
    int t = threadIdx.x;
    int i = blockIdx.x * 256 + t;
    int v = (i < N_NODES) ? deg[i] : 0;
    int incl = block_incl_scan256(v, sm, t);
    int excl = incl - v + partials[blockIdx.x];
    if (i < N_NODES) { rowptr[i] = excl; cursor[i] = excl; }
    if (blockIdx.x == 0 && t == 0) rowptr[N_NODES] = N_EDGES;
}

__global__ void scatter_kernel(const int* __restrict__ ei,
                               const float* __restrict__ ea,
                               int* __restrict__ cursor,
                               int4* __restrict__ edata) {
    int e = blockIdx.x * blockDim.x + threadIdx.x;
    if (e < N_EDGES) {
        int dst = ei[N_EDGES + e];
        int pos = atomicAdd(&cursor[dst], 1);
        edata[pos] = make_int4(ei[e],
                               __float_as_int(ea[3 * e]),
                               __float_as_int(ea[3 * e + 1]),
                               __float_as_int(ea[3 * e + 2]));
    }
}

// ===========================================================================
// Layer-1 gather (K=64, f32 input) — R9/R12-proven fingerprint, unchanged.
// 128 threads, NPB=8, one node per 64-lane half.
// ===========================================================================
__global__ void gather64_kernel(const float* __restrict__ xin,
                                const int4* __restrict__ edata,
                                const int* __restrict__ rowptr,
                                const float* __restrict__ elw,  // [3, 64]
                                const float* __restrict__ elb,  // [64]
                                unsigned short* __restrict__ sg) {  // bf16 [N, 64]
    constexpr int K = IN_CH;
    constexpr int NPB = 8;
    const int node0 = blockIdx.x * NPB;
    const int t = threadIdx.x;  // 0..127
    const int c = t & 63, half = t >> 6;
    const float w0 = elw[c], w1 = elw[K + c], w2 = elw[2 * K + c], eb = elb[c];

    auto term = [&](int4 e, float row) -> float {
        float ev = __int_as_float(e.y) * w0 + __int_as_float(e.z) * w1 +
                   __int_as_float(e.w) * w2 + eb;
        float m = row + ev;
        return m > 0.f ? m : 0.f;
    };

    for (int i = 0; i < NPB; i += 2) {
        int node = node0 + i + half;
        float acc = xin[(size_t)node * K + c];
        int jb = rowptr[node], je = rowptr[node + 1];
        int j = jb;
        for (; j + 8 <= je; j += 8) {
            int4 e0 = edata[j],     e1 = edata[j + 1], e2 = edata[j + 2], e3 = edata[j + 3];
            int4 e4 = edata[j + 4], e5 = edata[j + 5], e6 = edata[j + 6], e7 = edata[j + 7];
            float r0 = xin[(size_t)e0.x * K + c];
            float r1 = xin[(size_t)e1.x * K + c];
            float r2 = xin[(size_t)e2.x * K + c];
            float r3 = xin[(size_t)e3.x * K + c];
            float r4 = xin[(size_t)e4.x * K + c];
            float r5 = xin[(size_t)e5.x * K + c];
            float r6 = xin[(size_t)e6.x * K + c];
            float r7 = xin[(size_t)e7.x * K + c];
            acc += term(e0, r0) + term(e1, r1) + term(e2, r2) + term(e3, r3)
                 + term(e4, r4) + term(e5, r5) + term(e6, r6) + term(e7, r7);
        }
        for (; j + 4 <= je; j += 4) {
            int4 e0 = edata[j], e1 = edata[j + 1], e2 = edata[j + 2], e3 = edata[j + 3];
            float r0 = xin[(size_t)e0.x * K + c];
            float r1 = xin[(size_t)e1.x * K + c];
            float r2 = xin[(size_t)e2.x * K + c];
            float r3 = xin[(size_t)e3.x * K + c];
            acc += term(e0, r0) + term(e1, r1) + term(e2, r2) + term(e3, r3);
        }
        for (; j < je; j++) {
            int4 e0 = edata[j];
            acc += term(e0, xin[(size_t)e0.x * K + c]);
        }
        sg[(size_t)node * K + c] = f2bf(acc);
    }
}

// ===========================================================================
// Layer-2 gather (K=128, bf16 input), PACKED: one wave per node, each lane
// holds 2 channels (u32 = bf16x2) -> 1 edata broadcast + 1 row-load per edge
// (vs 2+2 in the split form). Standalone-safe: R10 proved the R6 collapse
// came from MFMA fusion, not this packing. 256 threads = 4 waves, NPW=4.
// ===========================================================================
__global__ void gather128_kernel(const unsigned short* __restrict__ xin,  // bf16 [N,128]
                                 const int4* __restrict__ edata,
                                 const int* __restrict__ rowptr,
                                 const float* __restrict__ elw,  // [3, 128]
                                 const float* __restrict__ elb,  // [128]
                                 unsigned short* __restrict__ sg) {  // bf16 [N, 128]
    constexpr int NPW = 4;
    const int t = threadIdx.x;
    const int w = t >> 6, l = t & 63;
    const unsigned* x32 = (const unsigned*)xin;       // row = 64 uints
    unsigned* sg32 = (unsigned*)sg;
    const int c0 = 2 * l;
    const float w00 = elw[c0],           w01 = elw[c0 + 1];
    const float w10 = elw[HID + c0],     w11 = elw[HID + c0 + 1];
    const float w20 = elw[2 * HID + c0], w21 = elw[2 * HID + c0 + 1];
    const float eb0 = elb[c0],           eb1 = elb[c0 + 1];
    const int node0 = (blockIdx.x * 4 + w) * NPW;

    for (int ni = 0; ni < NPW; ni++) {
        int node = node0 + ni;
        unsigned sv = x32[(size_t)node * 64 + l];
        float acc0 = bf2f((unsigned short)(sv & 0xFFFF));
        float acc1 = bf2f((unsigned short)(sv >> 16));
        auto term2 = [&](int4 e, unsigned r) {
            float A0 = __int_as_float(e.y), A1 = __int_as_float(e.z), A2 = __int_as_float(e.w);
            float ev0 = A0 * w00 + A1 * w10 + A2 * w20 + eb0;
            float ev1 = A0 * w01 + A1 * w11 + A2 * w21 + eb1;
            float m0 = bf2f((unsigned short)(r & 0xFFFF)) + ev0;
            float m1 = bf2f((unsigned short)(r >> 16)) + ev1;
            acc0 += m0 > 0.f ? m0 : 0.f;
            acc1 += m1 > 0.f ? m1 : 0.f;
        };
        int jb = rowptr[node], je = rowptr[node + 1];
        int j = jb;
        for (; j + 8 <= je; j += 8) {
            int4 e0 = edata[j],     e1 = edata[j + 1], e2 = edata[j + 2], e3 = edata[j + 3];
            int4 e4 = edata[j + 4], e5 = edata[j + 5], e6 = edata[j + 6], e7 = edata[j + 7];
            unsigned r0 = x32[(size_t)e0.x * 64 + l];
            unsigned r1 = x32[(size_t)e1.x * 64 + l];
            unsigned r2 = x32[(size_t)e2.x * 64 + l];
            unsigned r3 = x32[(size_t)e3.x * 64 + l];
            unsigned r4 = x32[(size_t)e4.x * 64 + l];
            unsigned r5 = x32[(size_t)e5.x * 64 + l];
            unsigned r6 = x32[(size_t)e6.x * 64 + l];
            unsigned r7 = x32[(size_t)e7.x * 64 + l];
            term2(e0, r0); term2(e1, r1); term2(e2, r2); term2(e3, r3);
            term2(e4, r4); term2(e5, r5); term2(e6, r6); term2(e7, r7);
        }
        for (; j + 4 <= je; j += 4) {
            int4 e0 = edata[j], e1 = edata[j + 1], e2 = edata[j + 2], e3 = edata[j + 3];
            unsigned r0 = x32[(size_t)e0.x * 64 + l];
            unsigned r1 = x32[(size_t)e1.x * 64 + l];
            unsigned r2 = x32[(size_t)e2.x * 64 + l];
            unsigned r3 = x32[(size_t)e3.x * 64 + l];
            term2(e0, r0); term2(e1, r1); term2(e2, r2); term2(e3, r3);
        }
        for (; j < je; j++) {
            int4 e0 = edata[j];
            term2(e0, x32[(size_t)e0.x * 64 + l]);
        }
        sg32[(size_t)node * 64 + l] = (unsigned)f2bf(acc0) | ((unsigned)f2bf(acc1) << 16);
    }
}

// ===========================================================================
// Standalone MFMA MLP — R12-proven (MFMA body + LDS-staged epilogue).
// ===========================================================================
template <int K, bool POOL>
__global__ __launch_bounds__(256)
void mlp_mfma_kernel(const unsigned short* __restrict__ sg,   // bf16 [N_PAD, K]
                     const unsigned short* __restrict__ waT,  // bf16 [HID, K]
                     const float* __restrict__ ba,
                     const unsigned short* __restrict__ wbT,  // bf16 [HID, HID]
                     const float* __restrict__ bb,
                     void* __restrict__ outv,                 // bf16 h or f32 psum
                     const int* __restrict__ batch) {
    constexpr int HSTR = 136;      // shorts
    constexpr int OSTR = HID + 4;  // f32
    __shared__ __align__(16) unsigned short sHid[4][16 * HSTR];  // 17.4 KB
    __shared__ __align__(16) float sOut[64 * OSTR];              // 33.8 KB
    const int t = threadIdx.x;
    const int w = t >> 6, l = t & 63;
    const int i16 = l & 15, q = l >> 4;
    const int blk0 = blockIdx.x * 64;
    const int row0 = blk0 + w * 16;   // this wave's 16 rows

    // ---- layer A: [16 x K] @ waT -> relu -> own LDS buffer ----
    bf16x8 aA[K / 32];
    #pragma unroll
    for (int s = 0; s < K / 32; s++)
        aA[s] = *(const bf16x8*)&sg[(size_t)(row0 + i16) * K + s * 32 + q * 8];
    unsigned short* myHid = sHid[w];
    #pragma unroll
    for (int ct = 0; ct < 8; ct++) {
        int col = ct * 16 + i16;
        float bv = ba[col];
        f32x4 acc = (f32x4){bv, bv, bv, bv};
        #pragma unroll
        for (int s = 0; s < K / 32; s++) {
            bf16x8 b = *(const bf16x8*)&waT[(size_t)col * K + s * 32 + q * 8];
            acc = __builtin_amdgcn_mfma_f32_16x16x32_bf16(aA[s], b, acc, 0, 0, 0);
        }
        #pragma unroll
        for (int r = 0; r < 4; r++) {
            float v = acc[r] > 0.f ? acc[r] : 0.f;
            myHid[(q * 4 + r) * HSTR + col] = f2bf(v);
        }
    }
    __syncthreads();

    // ---- layer B: [16 x 128] @ wbT -> relu -> sOut (f32 LDS) ----
    bf16x8 aB[4];
    #pragma unroll
    for (int s = 0; s < 4; s++)
        aB[s] = *(const bf16x8*)&myHid[i16 * HSTR + s * 32 + q * 8];
    #pragma unroll
    for (int ct = 0; ct < 8; ct++) {
        int col = ct * 16 + i16;
        float bv = bb[col];
        f32x4 acc = (f32x4){bv, bv, bv, bv};
        #pragma unroll
        for (int s = 0; s < 4; s++) {
            bf16x8 b = *(const bf16x8*)&wbT[(size_t)col * HID + s * 32 + q * 8];
            acc = __builtin_amdgcn_mfma_f32_16x16x32_bf16(aB[s], b, acc, 0, 0, 0);
        }
        #pragma unroll
        for (int r = 0; r < 4; r++) {
            float v = acc[r] > 0.f ? acc[r] : 0.f;
            sOut[(w * 16 + q * 4 + r) * OSTR + col] = v;
        }
    }
    __syncthreads();

    // ---- epilogue (R12-proven) ----
    if (POOL) {
        if (t < HID) {
            float* psum = (float*)outv;
            float acc = 0.f;
            int curg = batch[blk0];
            for (int row = 0; row < 64; row++) {
                int node = blk0 + row;
                if (node >= N_NODES) break;
                int g = batch[node];
                if (g != curg) {
                    atomicAdd(&psum[curg * HID + t], acc);
                    acc = 0.f; curg = g;
                }
                acc += sOut[row * OSTR + t];
            }
            atomicAdd(&psum[curg * HID + t], acc);
        }
    } else {
        unsigned short* hout = (unsigned short*)outv;
        for (int idx = t; idx < 64 * 16; idx += 256) {
            int row = idx >> 4, ch = idx & 15;   // ch = 16B chunk (8 bf16)
            int node = blk0 + row;
            if (node < N_NODES) {
                float4 f0 = *(const float4*)&sOut[row * OSTR + ch * 8];
                float4 f1 = *(const float4*)&sOut[row * OSTR + ch * 8 + 4];
                uint4 u;
                u.x = (unsigned)f2bf(f0.x) | ((unsigned)f2bf(f0.y) << 16);
                u.y = (unsigned)f2bf(f0.z) | ((unsigned)f2bf(f0.w) << 16);
                u.z = (unsigned)f2bf(f1.x) | ((unsigned)f2bf(f1.y) << 16);
                u.w = (unsigned)f2bf(f1.z) | ((unsigned)f2bf(f1.w) << 16);
                *(uint4*)&hout[(size_t)node * HID + ch * 8] = u;
            }
        }
    }
}

// ---------------------------------------------------------------------------
// Pool mean: batch is SORTED -> count[g] by binary search (wave-uniform).
// ---------------------------------------------------------------------------
__global__ void pool_div_kernel(const float* __restrict__ sums,
                                const int* __restrict__ batch,
                                float* __restrict__ out) {
    int i = blockIdx.x * blockDim.x + threadIdx.x;
    if (i >= N_GRAPHS * HID) return;
    int g = i / HID;
    int lo = 0, hi = N_NODES;
    while (lo < hi) { int mid = (lo + hi) >> 1; if (batch[mid] < g) lo = mid + 1; else hi = mid; }
    int start = lo;
    lo = 0; hi = N_NODES;
    while (lo < hi) { int mid = (lo + hi) >> 1; if (batch[mid] <= g) lo = mid + 1; else hi = mid; }
    float c = (float)(lo - start);
    out[i] = sums[i] / (c > 1.0f ? c : 1.0f);
}

extern "C" void kernel_launch(void* const* d_in, const int* in_sizes, int n_in,
                              void* d_out, int out_size, void* d_ws, size_t ws_size,
                              hipStream_t stream) {
    const float* x    = (const float*)d_in[0];
    const int*   ei   = (const int*)d_in[1];
    const float* ea   = (const float*)d_in[2];
    const int*   batch= (const int*)d_in[3];
    const float* el1w = (const float*)d_in[4];
    const float* el1b = (const float*)d_in[5];
    const float* w1a  = (const float*)d_in[6];
    const float* b1a  = (const float*)d_in[7];
    const float* w1b  = (const float*)d_in[8];
    const float* b1b  = (const float*)d_in[9];
    const float* el2w = (const float*)d_in[10];
    const float* el2b = (const float*)d_in[11];
    const float* w2a  = (const float*)d_in[12];
    const float* b2a  = (const float*)d_in[13];
    const float* w2b  = (const float*)d_in[14];
    const float* b2b  = (const float*)d_in[15];
    float* out = (float*)d_out;

    // workspace layout (16B-aligned sections)
    int4*  edata    = (int4*)d_ws;                      // [E] {src,a0,a1,a2}   9.6 MB
    float* psum     = (float*)(edata + N_EDGES);        // [G*HID] 8192 f32
    int*   deg      = (int*)(psum + N_GRAPHS * HID);    // [N]
    int*   cursor   = deg + N_NODES;                    // [N]
    int*   rowptr   = cursor + N_NODES;                 // [N+1]
    int*   partials = rowptr + N_NODES + 1;             // [256]
    // ints so far: 8192+50000+50000+50001+256 = 158449; pad to 158452 (16B mult)
    unsigned short* hbf  = (unsigned short*)((char*)psum + (size_t)158452 * 4);  // bf16 [N,HID]
    unsigned short* sgbuf= hbf + (size_t)N_NODES * HID;  // bf16 [N_PAD, 128] (layer1 uses stride 64)
    unsigned short* waT1 = sgbuf + (size_t)N_PAD * HID;  // bf16 [128, 64]
    unsigned short* wbT1 = waT1 + HID * IN_CH;           // bf16 [128, 128]
    unsigned short* waT2 = wbT1 + HID * HID;             // bf16 [128, 128]
    unsigned short* wbT2 = waT2 + HID * HID;             // bf16 [128, 128]

    // ---- prep (1 dispatch): zero deg+psum, transpose 4 weights ----
    prep_kernel<<<(N_NODES + 255) / 256, 256, 0, stream>>>(
        w1a, w1b, w2a, w2b, waT1, wbT1, waT2, wbT2, deg, psum);
    // ---- CSR build ----
    hist_kernel<<<(N_EDGES + 255) / 256, 256, 0, stream>>>(ei, deg);
    scan1_kernel<<<SCAN_BLOCKS, 256, 0, stream>>>(deg, partials);
    scan2_kernel<<<1, 256, 0, stream>>>(partials);
    scan3_kernel<<<SCAN_BLOCKS, 256, 0, stream>>>(deg, partials, rowptr, cursor);
    scatter_kernel<<<(N_EDGES + 255) / 256, 256, 0, stream>>>(ei, ea, cursor, edata);

    // ---- layer 1: f32 gather -> sg (bf16) ; MFMA MLP -> hbf (bf16) ----
    gather64_kernel<<<N_NODES / 8, 128, 0, stream>>>(
        x, edata, rowptr, el1w, el1b, sgbuf);
    mlp_mfma_kernel<IN_CH, false><<<N_PAD / 64, 256, 0, stream>>>(
        sgbuf, waT1, b1a, wbT1, b1b, hbf, nullptr);

    // ---- layer 2: packed bf16 gather -> sg ; MFMA MLP + LDS-reduced pool ----
    gather128_kernel<<<N_NODES / 16, 256, 0, stream>>>(
        hbf, edata, rowptr, el2w, el2b, sgbuf);
    mlp_mfma_kernel<HID, true><<<N_PAD / 64, 256, 0, stream>>>(
        sgbuf, waT2, b2a, wbT2, b2b, psum, batch);

    // ---- mean (count via binary search on sorted batch) ----
    pool_div_kernel<<<(N_GRAPHS * HID + 255) / 256, 256, 0, stream>>>(psum, batch, out);
}

// Round 14
// 306.821 us; speedup vs baseline: 1.6935x; 1.0048x over previous
//
#include <hip/hip_runtime.h>

#define N_NODES 50000
#define N_EDGES 600000
#define N_PAD 50048        // N rounded up to 64 (mlp tiles)
#define IN_CH 64
#define HID 128
#define N_GRAPHS 64
#define SCAN_BLOCKS 196   // ceil(N_NODES/256)

typedef __attribute__((ext_vector_type(8))) short bf16x8;
typedef __attribute__((ext_vector_type(4))) float f32x4;

// ---- bf16 helpers (manual, RNE) ----
__device__ __forceinline__ float bf2f(unsigned short u) {
    union { unsigned int i; float f; } v; v.i = ((unsigned int)u) << 16; return v.f;
}
__device__ __forceinline__ unsigned short f2bf(float f) {
    union { float f; unsigned int i; } v; v.f = f;
    unsigned int u = v.i;
    return (unsigned short)((u + 0x7FFFu + ((u >> 16) & 1u)) >> 16);
}

// ===========================================================================
// prep kernel: zero deg + zero psum + all 4 weight transposes in ONE dispatch.
// ===========================================================================
__global__ void prep_kernel(const float* __restrict__ w1a, const float* __restrict__ w1b,
                            const float* __restrict__ w2a, const float* __restrict__ w2b,
                            unsigned short* __restrict__ waT1, unsigned short* __restrict__ wbT1,
                            unsigned short* __restrict__ waT2, unsigned short* __restrict__ wbT2,
                            int* __restrict__ deg, float* __restrict__ psum) {
    int i = blockIdx.x * blockDim.x + threadIdx.x;
    if (i < N_NODES) deg[i] = 0;
    if (i < N_GRAPHS * HID) psum[i] = 0.f;
    if (i < IN_CH * HID) {               // w1a is [64,128]
        int k = i / HID, n = i % HID;
        waT1[n * IN_CH + k] = f2bf(w1a[i]);
    }
    if (i < HID * HID) {                 // the three [128,128] weights
        int k = i / HID, n = i % HID;
        wbT1[n * HID + k] = f2bf(w1b[i]);
        waT2[n * HID + k] = f2bf(w2a[i]);
        wbT2[n * HID + k] = f2bf(w2b[i]);
    }
}

// ===========================================================================
// CSR build. R13 lesson: 1-edge-per-thread scatter = zero ILP on the
// returning atomic + dependent store chain (44.8us, VALUBusy 0.5%).
// Now 4 edges/thread: int4/float4 batched loads, 4 independent atomics.
// ===========================================================================
__global__ void hist_kernel(const int* __restrict__ ei, int* __restrict__ deg) {
    int base = (blockIdx.x * blockDim.x + threadIdx.x) * 4;
    if (base < N_EDGES) {   // N_EDGES % 4 == 0, no tail
        int4 d = *(const int4*)(ei + N_EDGES + base);
        atomicAdd(&deg[d.x], 1);
        atomicAdd(&deg[d.y], 1);
        atomicAdd(&deg[d.z], 1);
        atomicAdd(&deg[d.w], 1);
    }
}

__device__ __forceinline__ int block_incl_scan256(int v, int* sm, int t) {
    int val = v;
    sm[t] = val; __syncthreads();
    #pragma unroll
    for (int off = 1; off < 256; off <<= 1) {
        int n = (t >= off) ? sm[t - off] : 0;
        __syncthreads();
        val += n; sm[t] = val; __syncthreads();
    }
    return val;
}

__global__ void scan1_kernel(const int* __restrict__ deg, int* __restrict__ partials) {
    __shared__ int sm[256];
    int t = threadIdx.x;
    int i = blockIdx.x * 256 + t;
    int v = (i < N_NODES) ? deg[i] : 0;
    sm[t] = v; __syncthreads();
    for (int off = 128; off > 0; off >>= 1) {
        if (t < off) sm[t] += sm[t + off];
        __syncthreads();
    }
    if (t == 0) partials[blockIdx.x] = sm[0];
}

__global__ void scan2_kernel(int* __restrict__ partials) {
    __shared__ int sm[256];
    int t = threadIdx.x;
    int v = (t < SCAN_BLOCKS) ? partials[t] : 0;
    int incl = block_incl_scan256(v, sm, t);
    if (t < SCAN_BLOCKS) partials[t] = incl - v;
}

__global__ void scan3_kernel(const int* __restrict__ deg,
                             const int* __restrict__ partials,
                             int* __restrict__ rowptr,
                             int* __restrict__ cursor) {
    __shared__ int sm[256];
    int t = threadIdx.x;
    int i = blockIdx.x * 256 + t;
    int v = (i < N_NODES) ? deg[i] : 0;
    int incl = block_incl_scan256(v, sm, t);
    int excl = incl - v + partials[blockIdx.x];
    if (i < N_NODES) { rowptr[i] = excl; cursor[i] = excl; }
    if (blockIdx.x == 0 && t == 0) rowptr[N_NODES] = N_EDGES;
}

__global__ void scatter_kernel(const int* __restrict__ ei,
                               const float* __restrict__ ea,
                               int* __restrict__ cursor,
                               int4* __restrict__ edata) {
    int base = (blockIdx.x * blockDim.x + threadIdx.x) * 4;
    if (base >= N_EDGES) return;   // N_EDGES % 4 == 0, no tail
    int4 s = *(const int4*)(ei + base);
    int4 d = *(const int4*)(ei + N_EDGES + base);
    const float4* ea4 = (const float4*)(ea + (size_t)base * 3);
    float4 A = ea4[0], B = ea4[1], C = ea4[2];
    // 4 independent returning atomics -> 4-deep latency overlap
    int p0 = atomicAdd(&cursor[d.x], 1);
    int p1 = atomicAdd(&cursor[d.y], 1);
    int p2 = atomicAdd(&cursor[d.z], 1);
    int p3 = atomicAdd(&cursor[d.w], 1);
    edata[p0] = make_int4(s.x, __float_as_int(A.x), __float_as_int(A.y), __float_as_int(A.z));
    edata[p1] = make_int4(s.y, __float_as_int(A.w), __float_as_int(B.x), __float_as_int(B.y));
    edata[p2] = make_int4(s.z, __float_as_int(B.z), __float_as_int(B.w), __float_as_int(C.x));
    edata[p3] = make_int4(s.w, __float_as_int(C.y), __float_as_int(C.z), __float_as_int(C.w));
}

// ===========================================================================
// Layer-1 gather (K=64, f32 input) — R9/R12-proven fingerprint, unchanged.
// ===========================================================================
__global__ void gather64_kernel(const float* __restrict__ xin,
                                const int4* __restrict__ edata,
                                const int* __restrict__ rowptr,
                                const float* __restrict__ elw,  // [3, 64]
                                const float* __restrict__ elb,  // [64]
                                unsigned short* __restrict__ sg) {  // bf16 [N, 64]
    constexpr int K = IN_CH;
    constexpr int NPB = 8;
    const int node0 = blockIdx.x * NPB;
    const int t = threadIdx.x;  // 0..127
    const int c = t & 63, half = t >> 6;
    const float w0 = elw[c], w1 = elw[K + c], w2 = elw[2 * K + c], eb = elb[c];

    auto term = [&](int4 e, float row) -> float {
        float ev = __int_as_float(e.y) * w0 + __int_as_float(e.z) * w1 +
                   __int_as_float(e.w) * w2 + eb;
        float m = row + ev;
        return m > 0.f ? m : 0.f;
    };

    for (int i = 0; i < NPB; i += 2) {
        int node = node0 + i + half;
        float acc = xin[(size_t)node * K + c];
        int jb = rowptr[node], je = rowptr[node + 1];
        int j = jb;
        for (; j + 8 <= je; j += 8) {
            int4 e0 = edata[j],     e1 = edata[j + 1], e2 = edata[j + 2], e3 = edata[j + 3];
            int4 e4 = edata[j + 4], e5 = edata[j + 5], e6 = edata[j + 6], e7 = edata[j + 7];
            float r0 = xin[(size_t)e0.x * K + c];
            float r1 = xin[(size_t)e1.x * K + c];
            float r2 = xin[(size_t)e2.x * K + c];
            float r3 = xin[(size_t)e3.x * K + c];
            float r4 = xin[(size_t)e4.x * K + c];
            float r5 = xin[(size_t)e5.x * K + c];
            float r6 = xin[(size_t)e6.x * K + c];
            float r7 = xin[(size_t)e7.x * K + c];
            acc += term(e0, r0) + term(e1, r1) + term(e2, r2) + term(e3, r3)
                 + term(e4, r4) + term(e5, r5) + term(e6, r6) + term(e7, r7);
        }
        for (; j + 4 <= je; j += 4) {
            int4 e0 = edata[j], e1 = edata[j + 1], e2 = edata[j + 2], e3 = edata[j + 3];
            float r0 = xin[(size_t)e0.x * K + c];
            float r1 = xin[(size_t)e1.x * K + c];
            float r2 = xin[(size_t)e2.x * K + c];
            float r3 = xin[(size_t)e3.x * K + c];
            acc += term(e0, r0) + term(e1, r1) + term(e2, r2) + term(e3, r3);
        }
        for (; j < je; j++) {
            int4 e0 = edata[j];
            acc += term(e0, xin[(size_t)e0.x * K + c]);
        }
        sg[(size_t)node * K + c] = f2bf(acc);
    }
}

// ===========================================================================
// Layer-2 gather (K=128, bf16 input), packed u32 lanes — R13-proven.
// ===========================================================================
__global__ void gather128_kernel(const unsigned short* __restrict__ xin,  // bf16 [N,128]
                                 const int4* __restrict__ edata,
                                 const int* __restrict__ rowptr,
                                 const float* __restrict__ elw,  // [3, 128]
                                 const float* __restrict__ elb,  // [128]
                                 unsigned short* __restrict__ sg) {  // bf16 [N, 128]
    constexpr int NPW = 4;
    const int t = threadIdx.x;
    const int w = t >> 6, l = t & 63;
    const unsigned* x32 = (const unsigned*)xin;       // row = 64 uints
    unsigned* sg32 = (unsigned*)sg;
    const int c0 = 2 * l;
    const float w00 = elw[c0],           w01 = elw[c0 + 1];
    const float w10 = elw[HID + c0],     w11 = elw[HID + c0 + 1];
    const float w20 = elw[2 * HID + c0], w21 = elw[2 * HID + c0 + 1];
    const float eb0 = elb[c0],           eb1 = elb[c0 + 1];
    const int node0 = (blockIdx.x * 4 + w) * NPW;

    for (int ni = 0; ni < NPW; ni++) {
        int node = node0 + ni;
        unsigned sv = x32[(size_t)node * 64 + l];
        float acc0 = bf2f((unsigned short)(sv & 0xFFFF));
        float acc1 = bf2f((unsigned short)(sv >> 16));
        auto term2 = [&](int4 e, unsigned r) {
            float A0 = __int_as_float(e.y), A1 = __int_as_float(e.z), A2 = __int_as_float(e.w);
            float ev0 = A0 * w00 + A1 * w10 + A2 * w20 + eb0;
            float ev1 = A0 * w01 + A1 * w11 + A2 * w21 + eb1;
            float m0 = bf2f((unsigned short)(r & 0xFFFF)) + ev0;
            float m1 = bf2f((unsigned short)(r >> 16)) + ev1;
            acc0 += m0 > 0.f ? m0 : 0.f;
            acc1 += m1 > 0.f ? m1 : 0.f;
        };
        int jb = rowptr[node], je = rowptr[node + 1];
        int j = jb;
        for (; j + 8 <= je; j += 8) {
            int4 e0 = edata[j],     e1 = edata[j + 1], e2 = edata[j + 2], e3 = edata[j + 3];
            int4 e4 = edata[j + 4], e5 = edata[j + 5], e6 = edata[j + 6], e7 = edata[j + 7];
            unsigned r0 = x32[(size_t)e0.x * 64 + l];
            unsigned r1 = x32[(size_t)e1.x * 64 + l];
            unsigned r2 = x32[(size_t)e2.x * 64 + l];
            unsigned r3 = x32[(size_t)e3.x * 64 + l];
            unsigned r4 = x32[(size_t)e4.x * 64 + l];
            unsigned r5 = x32[(size_t)e5.x * 64 + l];
            unsigned r6 = x32[(size_t)e6.x * 64 + l];
            unsigned r7 = x32[(size_t)e7.x * 64 + l];
            term2(e0, r0); term2(e1, r1); term2(e2, r2); term2(e3, r3);
            term2(e4, r4); term2(e5, r5); term2(e6, r6); term2(e7, r7);
        }
        for (; j + 4 <= je; j += 4) {
            int4 e0 = edata[j], e1 = edata[j + 1], e2 = edata[j + 2], e3 = edata[j + 3];
            unsigned r0 = x32[(size_t)e0.x * 64 + l];
            unsigned r1 = x32[(size_t)e1.x * 64 + l];
            unsigned r2 = x32[(size_t)e2.x * 64 + l];
            unsigned r3 = x32[(size_t)e3.x * 64 + l];
            term2(e0, r0); term2(e1, r1); term2(e2, r2); term2(e3, r3);
        }
        for (; j < je; j++) {
            int4 e0 = edata[j];
            term2(e0, x32[(size_t)e0.x * 64 + l]);
        }
        sg32[(size_t)node * 64 + l] = (unsigned)f2bf(acc0) | ((unsigned)f2bf(acc1) << 16);
    }
}

// ===========================================================================
// Standalone MFMA MLP — R12-proven (MFMA body + LDS-staged epilogue).
// ===========================================================================
template <int K, bool POOL>
__global__ __launch_bounds__(256)
void mlp_mfma_kernel(const unsigned short* __restrict__ sg,   // bf16 [N_PAD, K]
                     const unsigned short* __restrict__ waT,  // bf16 [HID, K]
                     const float* __restrict__ ba,
                     const unsigned short* __restrict__ wbT,  // bf16 [HID, HID]
                     const float* __restrict__ bb,
                     void* __restrict__ outv,                 // bf16 h or f32 psum
                     const int* __restrict__ batch) {
    constexpr int HSTR = 136;      // shorts
    constexpr int OSTR = HID + 4;  // f32
    __shared__ __align__(16) unsigned short sHid[4][16 * HSTR];  // 17.4 KB
    __shared__ __align__(16) float sOut[64 * OSTR];              // 33.8 KB
    const int t = threadIdx.x;
    const int w = t >> 6, l = t & 63;
    const int i16 = l & 15, q = l >> 4;
    const int blk0 = blockIdx.x * 64;
    const int row0 = blk0 + w * 16;   // this wave's 16 rows

    // ---- layer A: [16 x K] @ waT -> relu -> own LDS buffer ----
    bf16x8 aA[K / 32];
    #pragma unroll
    for (int s = 0; s < K / 32; s++)
        aA[s] = *(const bf16x8*)&sg[(size_t)(row0 + i16) * K + s * 32 + q * 8];
    unsigned short* myHid = sHid[w];
    #pragma unroll
    for (int ct = 0; ct < 8; ct++) {
        int col = ct * 16 + i16;
        float bv = ba[col];
        f32x4 acc = (f32x4){bv, bv, bv, bv};
        #pragma unroll
        for (int s = 0; s < K / 32; s++) {
            bf16x8 b = *(const bf16x8*)&waT[(size_t)col * K + s * 32 + q * 8];
            acc = __builtin_amdgcn_mfma_f32_16x16x32_bf16(aA[s], b, acc, 0, 0, 0);
        }
        #pragma unroll
        for (int r = 0; r < 4; r++) {
            float v = acc[r] > 0.f ? acc[r] : 0.f;
            myHid[(q * 4 + r) * HSTR + col] = f2bf(v);
        }
    }
    __syncthreads();

    // ---- layer B: [16 x 128] @ wbT -> relu -> sOut (f32 LDS) ----
    bf16x8 aB[4];
    #pragma unroll
    for (int s = 0; s < 4; s++)
        aB[s] = *(const bf16x8*)&myHid[i16 * HSTR + s * 32 + q * 8];
    #pragma unroll
    for (int ct = 0; ct < 8; ct++) {
        int col = ct * 16 + i16;
        float bv = bb[col];
        f32x4 acc = (f32x4){bv, bv, bv, bv};
        #pragma unroll
        for (int s = 0; s < 4; s++) {
            bf16x8 b = *(const bf16x8*)&wbT[(size_t)col * HID + s * 32 + q * 8];
            acc = __builtin_amdgcn_mfma_f32_16x16x32_bf16(aB[s], b, acc, 0, 0, 0);
        }
        #pragma unroll
        for (int r = 0; r < 4; r++) {
            float v = acc[r] > 0.f ? acc[r] : 0.f;
            sOut[(w * 16 + q * 4 + r) * OSTR + col] = v;
        }
    }
    __syncthreads();

    // ---- epilogue (R12-proven) ----
    if (POOL) {
        if (t < HID) {
            float* psum = (float*)outv;
            float acc = 0.f;
            int curg = batch[blk0];
            for (int row = 0; row < 64; row++) {
                int node = blk0 + row;
                if (node >= N_NODES) break;
                int g = batch[node];
                if (g != curg) {
                    atomicAdd(&psum[curg * HID + t], acc);
                    acc = 0.f; curg = g;
                }
                acc += sOut[row * OSTR + t];
            }
            atomicAdd(&psum[curg * HID + t], acc);
        }
    } else {
        unsigned short* hout = (unsigned short*)outv;
        for (int idx = t; idx < 64 * 16; idx += 256) {
            int row = idx >> 4, ch = idx & 15;   // ch = 16B chunk (8 bf16)
            int node = blk0 + row;
            if (node < N_NODES) {
                float4 f0 = *(const float4*)&sOut[row * OSTR + ch * 8];
                float4 f1 = *(const float4*)&sOut[row * OSTR + ch * 8 + 4];
                uint4 u;
                u.x = (unsigned)f2bf(f0.x) | ((unsigned)f2bf(f0.y) << 16);
                u.y = (unsigned)f2bf(f0.z) | ((unsigned)f2bf(f0.w) << 16);
                u.z = (unsigned)f2bf(f1.x) | ((unsigned)f2bf(f1.y) << 16);
                u.w = (unsigned)f2bf(f1.z) | ((unsigned)f2bf(f1.w) << 16);
                *(uint4*)&hout[(size_t)node * HID + ch * 8] = u;
            }
        }
    }
}

// ---------------------------------------------------------------------------
// Pool mean: batch is SORTED -> count[g] by binary search (wave-uniform).
// ---------------------------------------------------------------------------
__global__ void pool_div_kernel(const float* __restrict__ sums,
                                const int* __restrict__ batch,
                                float* __restrict__ out) {
    int i = blockIdx.x * blockDim.x + threadIdx.x;
    if (i >= N_GRAPHS * HID) return;
    int g = i / HID;
    int lo = 0, hi = N_NODES;
    while (lo < hi) { int mid = (lo + hi) >> 1; if (batch[mid] < g) lo = mid + 1; else hi = mid; }
    int start = lo;
    lo = 0; hi = N_NODES;
    while (lo < hi) { int mid = (lo + hi) >> 1; if (batch[mid] <= g) lo = mid + 1; else hi = mid; }
    float c = (float)(lo - start);
    out[i] = sums[i] / (c > 1.0f ? c : 1.0f);
}

extern "C" void kernel_launch(void* const* d_in, const int* in_sizes, int n_in,
                              void* d_out, int out_size, void* d_ws, size_t ws_size,
                              hipStream_t stream) {
    const float* x    = (const float*)d_in[0];
    const int*   ei   = (const int*)d_in[1];
    const float* ea   = (const float*)d_in[2];
    const int*   batch= (const int*)d_in[3];
    const float* el1w = (const float*)d_in[4];
    const float* el1b = (const float*)d_in[5];
    const float* w1a  = (const float*)d_in[6];
    const float* b1a  = (const float*)d_in[7];
    const float* w1b  = (const float*)d_in[8];
    const float* b1b  = (const float*)d_in[9];
    const float* el2w = (const float*)d_in[10];
    const float* el2b = (const float*)d_in[11];
    const float* w2a  = (const float*)d_in[12];
    const float* b2a  = (const float*)d_in[13];
    const float* w2b  = (const float*)d_in[14];
    const float* b2b  = (const float*)d_in[15];
    float* out = (float*)d_out;

    // workspace layout (16B-aligned sections)
    int4*  edata    = (int4*)d_ws;                      // [E] {src,a0,a1,a2}   9.6 MB
    float* psum     = (float*)(edata + N_EDGES);        // [G*HID] 8192 f32
    int*   deg      = (int*)(psum + N_GRAPHS * HID);    // [N]
    int*   cursor   = deg + N_NODES;                    // [N]
    int*   rowptr   = cursor + N_NODES;                 // [N+1]
    int*   partials = rowptr + N_NODES + 1;             // [256]
    // ints so far: 8192+50000+50000+50001+256 = 158449; pad to 158452 (16B mult)
    unsigned short* hbf  = (unsigned short*)((char*)psum + (size_t)158452 * 4);  // bf16 [N,HID]
    unsigned short* sgbuf= hbf + (size_t)N_NODES * HID;  // bf16 [N_PAD, 128] (layer1 uses stride 64)
    unsigned short* waT1 = sgbuf + (size_t)N_PAD * HID;  // bf16 [128, 64]
    unsigned short* wbT1 = waT1 + HID * IN_CH;           // bf16 [128, 128]
    unsigned short* waT2 = wbT1 + HID * HID;             // bf16 [128, 128]
    unsigned short* wbT2 = waT2 + HID * HID;             // bf16 [128, 128]

    // ---- prep (1 dispatch): zero deg+psum, transpose 4 weights ----
    prep_kernel<<<(N_NODES + 255) / 256, 256, 0, stream>>>(
        w1a, w1b, w2a, w2b, waT1, wbT1, waT2, wbT2, deg, psum);
    // ---- CSR build (4 edges/thread ILP in hist+scatter) ----
    hist_kernel<<<(N_EDGES / 4 + 255) / 256, 256, 0, stream>>>(ei, deg);
    scan1_kernel<<<SCAN_BLOCKS, 256, 0, stream>>>(deg, partials);
    scan2_kernel<<<1, 256, 0, stream>>>(partials);
    scan3_kernel<<<SCAN_BLOCKS, 256, 0, stream>>>(deg, partials, rowptr, cursor);
    scatter_kernel<<<(N_EDGES / 4 + 255) / 256, 256, 0, stream>>>(ei, ea, cursor, edata);

    // ---- layer 1: f32 gather -> sg (bf16) ; MFMA MLP -> hbf (bf16) ----
    gather64_kernel<<<N_NODES / 8, 128, 0, stream>>>(
        x, edata, rowptr, el1w, el1b, sgbuf);
    mlp_mfma_kernel<IN_CH, false><<<N_PAD / 64, 256, 0, stream>>>(
        sgbuf, waT1, b1a, wbT1, b1b, hbf, nullptr);

    // ---- layer 2: packed bf16 gather -> sg ; MFMA MLP + LDS-reduced pool ----
    gather128_kernel<<<N_NODES / 16, 256, 0, stream>>>(
        hbf, edata, rowptr, el2w, el2b, sgbuf);
    mlp_mfma_kernel<HID, true><<<N_PAD / 64, 256, 0, stream>>>(
        sgbuf, waT2, b2a, wbT2, b2b, psum, batch);

    // ---- mean (count via binary search on sorted batch) ----
    pool_div_kernel<<<(N_GRAPHS * HID + 255) / 256, 256, 0, stream>>>(psum, batch, out);
}

// Round 15
// 299.016 us; speedup vs baseline: 1.7378x; 1.0261x over previous
//
#include <hip/hip_runtime.h>

#define N_NODES 50000
#define N_EDGES 600000
#define N_PAD 50048        // N rounded up to 64 (mlp tiles)
#define IN_CH 64
#define HID 128
#define N_GRAPHS 64
#define SCAN_BLOCKS 196   // ceil(N_NODES/256)

typedef __attribute__((ext_vector_type(8))) short bf16x8;
typedef __attribute__((ext_vector_type(4))) float f32x4;

// ---- bf16 helpers (manual, RNE) ----
__device__ __forceinline__ float bf2f(unsigned short u) {
    union { unsigned int i; float f; } v; v.i = ((unsigned int)u) << 16; return v.f;
}
__device__ __forceinline__ unsigned short f2bf(float f) {
    union { float f; unsigned int i; } v; v.f = f;
    unsigned int u = v.i;
    return (unsigned short)((u + 0x7FFFu + ((u >> 16) & 1u)) >> 16);
}

// 8B edge record: x = src(u16) | a0(bf16)<<16 ; y = a1(bf16) | a2(bf16)<<16
// (R14 lesson: scatter is RMW-byte-bound, not latency-bound -> halve bytes)

// ===========================================================================
// prep kernel: zero deg + zero psum + all 4 weight transposes in ONE dispatch.
// ===========================================================================
__global__ void prep_kernel(const float* __restrict__ w1a, const float* __restrict__ w1b,
                            const float* __restrict__ w2a, const float* __restrict__ w2b,
                            unsigned short* __restrict__ waT1, unsigned short* __restrict__ wbT1,
                            unsigned short* __restrict__ waT2, unsigned short* __restrict__ wbT2,
                            int* __restrict__ deg, float* __restrict__ psum) {
    int i = blockIdx.x * blockDim.x + threadIdx.x;
    if (i < N_NODES) deg[i] = 0;
    if (i < N_GRAPHS * HID) psum[i] = 0.f;
    if (i < IN_CH * HID) {               // w1a is [64,128]
        int k = i / HID, n = i % HID;
        waT1[n * IN_CH + k] = f2bf(w1a[i]);
    }
    if (i < HID * HID) {                 // the three [128,128] weights
        int k = i / HID, n = i % HID;
        wbT1[n * HID + k] = f2bf(w1b[i]);
        waT2[n * HID + k] = f2bf(w2a[i]);
        wbT2[n * HID + k] = f2bf(w2b[i]);
    }
}

// ===========================================================================
// CSR build: counting-sort edges by dst into 8B records.
// ===========================================================================
__global__ void hist_kernel(const int* __restrict__ ei, int* __restrict__ deg) {
    int base = (blockIdx.x * blockDim.x + threadIdx.x) * 4;
    if (base < N_EDGES) {   // N_EDGES % 4 == 0, no tail
        int4 d = *(const int4*)(ei + N_EDGES + base);
        atomicAdd(&deg[d.x], 1);
        atomicAdd(&deg[d.y], 1);
        atomicAdd(&deg[d.z], 1);
        atomicAdd(&deg[d.w], 1);
    }
}

__device__ __forceinline__ int block_incl_scan256(int v, int* sm, int t) {
    int val = v;
    sm[t] = val; __syncthreads();
    #pragma unroll
    for (int off = 1; off < 256; off <<= 1) {
        int n = (t >= off) ? sm[t - off] : 0;
        __syncthreads();
        val += n; sm[t] = val; __syncthreads();
    }
    return val;
}

__global__ void scan1_kernel(const int* __restrict__ deg, int* __restrict__ partials) {
    __shared__ int sm[256];
    int t = threadIdx.x;
    int i = blockIdx.x * 256 + t;
    int v = (i < N_NODES) ? deg[i] : 0;
    sm[t] = v; __syncthreads();
    for (int off = 128; off > 0; off >>= 1) {
        if (t < off) sm[t] += sm[t + off];
        __syncthreads();
    }
    if (t == 0) partials[blockIdx.x] = sm[0];
}

__global__ void scan2_kernel(int* __restrict__ partials) {
    __shared__ int sm[256];
    int t = threadIdx.x;
    int v = (t < SCAN_BLOCKS) ? partials[t] : 0;
    int incl = block_incl_scan256(v, sm, t);
    if (t < SCAN_BLOCKS) partials[t] = incl - v;
}

__global__ void scan3_kernel(const int* __restrict__ deg,
                             const int* __restrict__ partials,
                             int* __restrict__ rowptr,
                             int* __restrict__ cursor) {
    __shared__ int sm[256];
    int t = threadIdx.x;
    int i = blockIdx.x * 256 + t;
    int v = (i < N_NODES) ? deg[i] : 0;
    int incl = block_incl_scan256(v, sm, t);
    int excl = incl - v + partials[blockIdx.x];
    if (i < N_NODES) { rowptr[i] = excl; cursor[i] = excl; }
    if (blockIdx.x == 0 && t == 0) rowptr[N_NODES] = N_EDGES;
}

__global__ void scatter_kernel(const int* __restrict__ ei,
                               const float* __restrict__ ea,
                               int* __restrict__ cursor,
                               uint2* __restrict__ edata) {
    int base = (blockIdx.x * blockDim.x + threadIdx.x) * 4;
    if (base >= N_EDGES) return;   // N_EDGES % 4 == 0, no tail
    int4 s = *(const int4*)(ei + base);
    int4 d = *(const int4*)(ei + N_EDGES + base);
    const float4* ea4 = (const float4*)(ea + (size_t)base * 3);
    float4 A = ea4[0], B = ea4[1], C = ea4[2];
    int p0 = atomicAdd(&cursor[d.x], 1);
    int p1 = atomicAdd(&cursor[d.y], 1);
    int p2 = atomicAdd(&cursor[d.z], 1);
    int p3 = atomicAdd(&cursor[d.w], 1);
    edata[p0] = make_uint2((unsigned)s.x | ((unsigned)f2bf(A.x) << 16),
                           (unsigned)f2bf(A.y) | ((unsigned)f2bf(A.z) << 16));
    edata[p1] = make_uint2((unsigned)s.y | ((unsigned)f2bf(A.w) << 16),
                           (unsigned)f2bf(B.x) | ((unsigned)f2bf(B.y) << 16));
    edata[p2] = make_uint2((unsigned)s.z | ((unsigned)f2bf(B.z) << 16),
                           (unsigned)f2bf(B.w) | ((unsigned)f2bf(C.x) << 16));
    edata[p3] = make_uint2((unsigned)s.w | ((unsigned)f2bf(C.y) << 16),
                           (unsigned)f2bf(C.z) | ((unsigned)f2bf(C.w) << 16));
}

// ===========================================================================
// Layer-1 gather (K=64, f32 input) — R9/R12-proven structure; edata now 8B.
// ===========================================================================
__global__ void gather64_kernel(const float* __restrict__ xin,
                                const uint2* __restrict__ edata,
                                const int* __restrict__ rowptr,
                                const float* __restrict__ elw,  // [3, 64]
                                const float* __restrict__ elb,  // [64]
                                unsigned short* __restrict__ sg) {  // bf16 [N, 64]
    constexpr int K = IN_CH;
    constexpr int NPB = 8;
    const int node0 = blockIdx.x * NPB;
    const int t = threadIdx.x;  // 0..127
    const int c = t & 63, half = t >> 6;
    const float w0 = elw[c], w1 = elw[K + c], w2 = elw[2 * K + c], eb = elb[c];

    auto term = [&](uint2 e, float row) -> float {
        float ev = bf2f((unsigned short)(e.x >> 16)) * w0 +
                   bf2f((unsigned short)(e.y & 0xFFFF)) * w1 +
                   bf2f((unsigned short)(e.y >> 16)) * w2 + eb;
        float m = row + ev;
        return m > 0.f ? m : 0.f;
    };

    for (int i = 0; i < NPB; i += 2) {
        int node = node0 + i + half;
        float acc = xin[(size_t)node * K + c];
        int jb = rowptr[node], je = rowptr[node + 1];
        int j = jb;
        for (; j + 8 <= je; j += 8) {
            uint2 e0 = edata[j],     e1 = edata[j + 1], e2 = edata[j + 2], e3 = edata[j + 3];
            uint2 e4 = edata[j + 4], e5 = edata[j + 5], e6 = edata[j + 6], e7 = edata[j + 7];
            float r0 = xin[(size_t)(e0.x & 0xFFFF) * K + c];
            float r1 = xin[(size_t)(e1.x & 0xFFFF) * K + c];
            float r2 = xin[(size_t)(e2.x & 0xFFFF) * K + c];
            float r3 = xin[(size_t)(e3.x & 0xFFFF) * K + c];
            float r4 = xin[(size_t)(e4.x & 0xFFFF) * K + c];
            float r5 = xin[(size_t)(e5.x & 0xFFFF) * K + c];
            float r6 = xin[(size_t)(e6.x & 0xFFFF) * K + c];
            float r7 = xin[(size_t)(e7.x & 0xFFFF) * K + c];
            acc += term(e0, r0) + term(e1, r1) + term(e2, r2) + term(e3, r3)
                 + term(e4, r4) + term(e5, r5) + term(e6, r6) + term(e7, r7);
        }
        for (; j + 4 <= je; j += 4) {
            uint2 e0 = edata[j], e1 = edata[j + 1], e2 = edata[j + 2], e3 = edata[j + 3];
            float r0 = xin[(size_t)(e0.x & 0xFFFF) * K + c];
            float r1 = xin[(size_t)(e1.x & 0xFFFF) * K + c];
            float r2 = xin[(size_t)(e2.x & 0xFFFF) * K + c];
            float r3 = xin[(size_t)(e3.x & 0xFFFF) * K + c];
            acc += term(e0, r0) + term(e1, r1) + term(e2, r2) + term(e3, r3);
        }
        for (; j < je; j++) {
            uint2 e0 = edata[j];
            acc += term(e0, xin[(size_t)(e0.x & 0xFFFF) * K + c]);
        }
        sg[(size_t)node * K + c] = f2bf(acc);
    }
}

// ===========================================================================
// Layer-2 gather (K=128, bf16 input), packed u32 lanes. NEW: two nodes per
// wave in LOCKSTEP (avg degree=12 -> the old 8-unroll fired once then
// dribbled; paired chains keep 8 row loads in flight throughout).
// ===========================================================================
__global__ void gather128_kernel(const unsigned short* __restrict__ xin,  // bf16 [N,128]
                                 const uint2* __restrict__ edata,
                                 const int* __restrict__ rowptr,
                                 const float* __restrict__ elw,  // [3, 128]
                                 const float* __restrict__ elb,  // [128]
                                 unsigned short* __restrict__ sg) {  // bf16 [N, 128]
    const int t = threadIdx.x;
    const int w = t >> 6, l = t & 63;
    const unsigned* x32 = (const unsigned*)xin;       // row = 64 uints
    unsigned* sg32 = (unsigned*)sg;
    const int c0 = 2 * l;
    const float w00 = elw[c0],           w01 = elw[c0 + 1];
    const float w10 = elw[HID + c0],     w11 = elw[HID + c0 + 1];
    const float w20 = elw[2 * HID + c0], w21 = elw[2 * HID + c0 + 1];
    const float eb0 = elb[c0],           eb1 = elb[c0 + 1];
    const int node0 = (blockIdx.x * 4 + w) * 4;

    for (int ni = 0; ni < 4; ni += 2) {
        int nA = node0 + ni, nB = node0 + ni + 1;
        unsigned svA = x32[(size_t)nA * 64 + l];
        unsigned svB = x32[(size_t)nB * 64 + l];
        float a0 = bf2f((unsigned short)(svA & 0xFFFF));
        float a1 = bf2f((unsigned short)(svA >> 16));
        float b0 = bf2f((unsigned short)(svB & 0xFFFF));
        float b1 = bf2f((unsigned short)(svB >> 16));

        auto term2 = [&](uint2 e, unsigned r, float& p0, float& p1) {
            float A0 = bf2f((unsigned short)(e.x >> 16));
            float A1 = bf2f((unsigned short)(e.y & 0xFFFF));
            float A2 = bf2f((unsigned short)(e.y >> 16));
            float ev0 = A0 * w00 + A1 * w10 + A2 * w20 + eb0;
            float ev1 = A0 * w01 + A1 * w11 + A2 * w21 + eb1;
            float m0 = bf2f((unsigned short)(r & 0xFFFF)) + ev0;
            float m1 = bf2f((unsigned short)(r >> 16)) + ev1;
            p0 += m0 > 0.f ? m0 : 0.f;
            p1 += m1 > 0.f ? m1 : 0.f;
        };

        int ja = rowptr[nA], jaE = rowptr[nA + 1];
        int jb = rowptr[nB], jbE = rowptr[nB + 1];
        // lockstep: 4 edges per node per iter -> 8 independent row loads
        while (ja + 4 <= jaE && jb + 4 <= jbE) {
            uint2 eA0 = edata[ja],     eA1 = edata[ja + 1], eA2 = edata[ja + 2], eA3 = edata[ja + 3];
            uint2 eB0 = edata[jb],     eB1 = edata[jb + 1], eB2 = edata[jb + 2], eB3 = edata[jb + 3];
            unsigned rA0 = x32[(size_t)(eA0.x & 0xFFFF) * 64 + l];
            unsigned rA1 = x32[(size_t)(eA1.x & 0xFFFF) * 64 + l];
            unsigned rA2 = x32[(size_t)(eA2.x & 0xFFFF) * 64 + l];
            unsigned rA3 = x32[(size_t)(eA3.x & 0xFFFF) * 64 + l];
            unsigned rB0 = x32[(size_t)(eB0.x & 0xFFFF) * 64 + l];
            unsigned rB1 = x32[(size_t)(eB1.x & 0xFFFF) * 64 + l];
            unsigned rB2 = x32[(size_t)(eB2.x & 0xFFFF) * 64 + l];
            unsigned rB3 = x32[(size_t)(eB3.x & 0xFFFF) * 64 + l];
            term2(eA0, rA0, a0, a1); term2(eA1, rA1, a0, a1);
            term2(eA2, rA2, a0, a1); term2(eA3, rA3, a0, a1);
            term2(eB0, rB0, b0, b1); term2(eB1, rB1, b0, b1);
            term2(eB2, rB2, b0, b1); term2(eB3, rB3, b0, b1);
            ja += 4; jb += 4;
        }
        // drain node A
        for (; ja + 4 <= jaE; ja += 4) {
            uint2 e0 = edata[ja], e1 = edata[ja + 1], e2 = edata[ja + 2], e3 = edata[ja + 3];
            unsigned r0 = x32[(size_t)(e0.x & 0xFFFF) * 64 + l];
            unsigned r1 = x32[(size_t)(e1.x & 0xFFFF) * 64 + l];
            unsigned r2 = x32[(size_t)(e2.x & 0xFFFF) * 64 + l];
            unsigned r3 = x32[(size_t)(e3.x & 0xFFFF) * 64 + l];
            term2(e0, r0, a0, a1); term2(e1, r1, a0, a1);
            term2(e2, r2, a0, a1); term2(e3, r3, a0, a1);
        }
        for (; ja < jaE; ja++) {
            uint2 e0 = edata[ja];
            term2(e0, x32[(size_t)(e0.x & 0xFFFF) * 64 + l], a0, a1);
        }
        // drain node B
        for (; jb + 4 <= jbE; jb += 4) {
            uint2 e0 = edata[jb], e1 = edata[jb + 1], e2 = edata[jb + 2], e3 = edata[jb + 3];
            unsigned r0 = x32[(size_t)(e0.x & 0xFFFF) * 64 + l];
            unsigned r1 = x32[(size_t)(e1.x & 0xFFFF) * 64 + l];
            unsigned r2 = x32[(size_t)(e2.x & 0xFFFF) * 64 + l];
            unsigned r3 = x32[(size_t)(e3.x & 0xFFFF) * 64 + l];
            term2(e0, r0, b0, b1); term2(e1, r1, b0, b1);
            term2(e2, r2, b0, b1); term2(e3, r3, b0, b1);
        }
        for (; jb < jbE; jb++) {
            uint2 e0 = edata[jb];
            term2(e0, x32[(size_t)(e0.x & 0xFFFF) * 64 + l], b0, b1);
        }
        sg32[(size_t)nA * 64 + l] = (unsigned)f2bf(a0) | ((unsigned)f2bf(a1) << 16);
        sg32[(size_t)nB * 64 + l] = (unsigned)f2bf(b0) | ((unsigned)f2bf(b1) << 16);
    }
}

// ===========================================================================
// Standalone MFMA MLP — R12-proven (MFMA body + LDS-staged epilogue).
// ===========================================================================
template <int K, bool POOL>
__global__ __launch_bounds__(256)
void mlp_mfma_kernel(const unsigned short* __restrict__ sg,   // bf16 [N_PAD, K]
                     const unsigned short* __restrict__ waT,  // bf16 [HID, K]
                     const float* __restrict__ ba,
                     const unsigned short* __restrict__ wbT,  // bf16 [HID, HID]
                     const float* __restrict__ bb,
                     void* __restrict__ outv,                 // bf16 h or f32 psum
                     const int* __restrict__ batch) {
    constexpr int HSTR = 136;      // shorts
    constexpr int OSTR = HID + 4;  // f32
    __shared__ __align__(16) unsigned short sHid[4][16 * HSTR];  // 17.4 KB
    __shared__ __align__(16) float sOut[64 * OSTR];              // 33.8 KB
    const int t = threadIdx.x;
    const int w = t >> 6, l = t & 63;
    const int i16 = l & 15, q = l >> 4;
    const int blk0 = blockIdx.x * 64;
    const int row0 = blk0 + w * 16;   // this wave's 16 rows

    // ---- layer A: [16 x K] @ waT -> relu -> own LDS buffer ----
    bf16x8 aA[K / 32];
    #pragma unroll
    for (int s = 0; s < K / 32; s++)
        aA[s] = *(const bf16x8*)&sg[(size_t)(row0 + i16) * K + s * 32 + q * 8];
    unsigned short* myHid = sHid[w];
    #pragma unroll
    for (int ct = 0; ct < 8; ct++) {
        int col = ct * 16 + i16;
        float bv = ba[col];
        f32x4 acc = (f32x4){bv, bv, bv, bv};
        #pragma unroll
        for (int s = 0; s < K / 32; s++) {
            bf16x8 b = *(const bf16x8*)&waT[(size_t)col * K + s * 32 + q * 8];
            acc = __builtin_amdgcn_mfma_f32_16x16x32_bf16(aA[s], b, acc, 0, 0, 0);
        }
        #pragma unroll
        for (int r = 0; r < 4; r++) {
            float v = acc[r] > 0.f ? acc[r] : 0.f;
            myHid[(q * 4 + r) * HSTR + col] = f2bf(v);
        }
    }
    __syncthreads();

    // ---- layer B: [16 x 128] @ wbT -> relu -> sOut (f32 LDS) ----
    bf16x8 aB[4];
    #pragma unroll
    for (int s = 0; s < 4; s++)
        aB[s] = *(const bf16x8*)&myHid[i16 * HSTR + s * 32 + q * 8];
    #pragma unroll
    for (int ct = 0; ct < 8; ct++) {
        int col = ct * 16 + i16;
        float bv = bb[col];
        f32x4 acc = (f32x4){bv, bv, bv, bv};
        #pragma unroll
        for (int s = 0; s < 4; s++) {
            bf16x8 b = *(const bf16x8*)&wbT[(size_t)col * HID + s * 32 + q * 8];
            acc = __builtin_amdgcn_mfma_f32_16x16x32_bf16(aB[s], b, acc, 0, 0, 0);
        }
        #pragma unroll
        for (int r = 0; r < 4; r++) {
            float v = acc[r] > 0.f ? acc[r] : 0.f;
            sOut[(w * 16 + q * 4 + r) * OSTR + col] = v;
        }
    }
    __syncthreads();

    // ---- epilogue (R12-proven) ----
    if (POOL) {
        if (t < HID) {
            float* psum = (float*)outv;
            float acc = 0.f;
            int curg = batch[blk0];
            for (int row = 0; row < 64; row++) {
                int node = blk0 + row;
                if (node >= N_NODES) break;
                int g = batch[node];
                if (g != curg) {
                    atomicAdd(&psum[curg * HID + t], acc);
                    acc = 0.f; curg = g;
                }
                acc += sOut[row * OSTR + t];
            }
            atomicAdd(&psum[curg * HID + t], acc);
        }
    } else {
        unsigned short* hout = (unsigned short*)outv;
        for (int idx = t; idx < 64 * 16; idx += 256) {
            int row = idx >> 4, ch = idx & 15;   // ch = 16B chunk (8 bf16)
            int node = blk0 + row;
            if (node < N_NODES) {
                float4 f0 = *(const float4*)&sOut[row * OSTR + ch * 8];
                float4 f1 = *(const float4*)&sOut[row * OSTR + ch * 8 + 4];
                uint4 u;
                u.x = (unsigned)f2bf(f0.x) | ((unsigned)f2bf(f0.y) << 16);
                u.y = (unsigned)f2bf(f0.z) | ((unsigned)f2bf(f0.w) << 16);
                u.z = (unsigned)f2bf(f1.x) | ((unsigned)f2bf(f1.y) << 16);
                u.w = (unsigned)f2bf(f1.z) | ((unsigned)f2bf(f1.w) << 16);
                *(uint4*)&hout[(size_t)node * HID + ch * 8] = u;
            }
        }
    }
}

// ---------------------------------------------------------------------------
// Pool mean: batch is SORTED -> count[g] by binary search (wave-uniform).
// ---------------------------------------------------------------------------
__global__ void pool_div_kernel(const float* __restrict__ sums,
                                const int* __restrict__ batch,
                                float* __restrict__ out) {
    int i = blockIdx.x * blockDim.x + threadIdx.x;
    if (i >= N_GRAPHS * HID) return;
    int g = i / HID;
    int lo = 0, hi = N_NODES;
    while (lo < hi) { int mid = (lo + hi) >> 1; if (batch[mid] < g) lo = mid + 1; else hi = mid; }
    int start = lo;
    lo = 0; hi = N_NODES;
    while (lo < hi) { int mid = (lo + hi) >> 1; if (batch[mid] <= g) lo = mid + 1; else hi = mid; }
    float c = (float)(lo - start);
    out[i] = sums[i] / (c > 1.0f ? c : 1.0f);
}

extern "C" void kernel_launch(void* const* d_in, const int* in_sizes, int n_in,
                              void* d_out, int out_size, void* d_ws, size_t ws_size,
                              hipStream_t stream) {
    const float* x    = (const float*)d_in[0];
    const int*   ei   = (const int*)d_in[1];
    const float* ea   = (const float*)d_in[2];
    const int*   batch= (const int*)d_in[3];
    const float* el1w = (const float*)d_in[4];
    const float* el1b = (const float*)d_in[5];
    const float* w1a  = (const float*)d_in[6];
    const float* b1a  = (const float*)d_in[7];
    const float* w1b  = (const float*)d_in[8];
    const float* b1b  = (const float*)d_in[9];
    const float* el2w = (const float*)d_in[10];
    const float* el2b = (const float*)d_in[11];
    const float* w2a  = (const float*)d_in[12];
    const float* b2a  = (const float*)d_in[13];
    const float* w2b  = (const float*)d_in[14];
    const float* b2b  = (const float*)d_in[15];
    float* out = (float*)d_out;

    // workspace layout (16B-aligned sections)
    uint2* edata    = (uint2*)d_ws;                     // [E] 8B records      4.8 MB
    float* psum     = (float*)(edata + N_EDGES);        // [G*HID] 8192 f32
    int*   deg      = (int*)(psum + N_GRAPHS * HID);    // [N]
    int*   cursor   = deg + N_NODES;                    // [N]
    int*   rowptr   = cursor + N_NODES;                 // [N+1]
    int*   partials = rowptr + N_NODES + 1;             // [256]
    // ints so far: 8192+50000+50000+50001+256 = 158449; pad to 158452 (16B mult)
    unsigned short* hbf  = (unsigned short*)((char*)psum + (size_t)158452 * 4);  // bf16 [N,HID]
    unsigned short* sgbuf= hbf + (size_t)N_NODES * HID;  // bf16 [N_PAD, 128] (layer1 uses stride 64)
    unsigned short* waT1 = sgbuf + (size_t)N_PAD * HID;  // bf16 [128, 64]
    unsigned short* wbT1 = waT1 + HID * IN_CH;           // bf16 [128, 128]
    unsigned short* waT2 = wbT1 + HID * HID;             // bf16 [128, 128]
    unsigned short* wbT2 = waT2 + HID * HID;             // bf16 [128, 128]

    // ---- prep (1 dispatch): zero deg+psum, transpose 4 weights ----
    prep_kernel<<<(N_NODES + 255) / 256, 256, 0, stream>>>(
        w1a, w1b, w2a, w2b, waT1, wbT1, waT2, wbT2, deg, psum);
    // ---- CSR build ----
    hist_kernel<<<(N_EDGES / 4 + 255) / 256, 256, 0, stream>>>(ei, deg);
    scan1_kernel<<<SCAN_BLOCKS, 256, 0, stream>>>(deg, partials);
    scan2_kernel<<<1, 256, 0, stream>>>(partials);
    scan3_kernel<<<SCAN_BLOCKS, 256, 0, stream>>>(deg, partials, rowptr, cursor);
    scatter_kernel<<<(N_EDGES / 4 + 255) / 256, 256, 0, stream>>>(ei, ea, cursor, edata);

    // ---- layer 1: f32 gather -> sg (bf16) ; MFMA MLP -> hbf (bf16) ----
    gather64_kernel<<<N_NODES / 8, 128, 0, stream>>>(
        x, edata, rowptr, el1w, el1b, sgbuf);
    mlp_mfma_kernel<IN_CH, false><<<N_PAD / 64, 256, 0, stream>>>(
        sgbuf, waT1, b1a, wbT1, b1b, hbf, nullptr);

    // ---- layer 2: paired-lockstep bf16 gather ; MFMA MLP + LDS pool ----
    gather128_kernel<<<N_NODES / 16, 256, 0, stream>>>(
        hbf, edata, rowptr, el2w, el2b, sgbuf);
    mlp_mfma_kernel<HID, true><<<N_PAD / 64, 256, 0, stream>>>(
        sgbuf, waT2, b2a, wbT2, b2b, psum, batch);

    // ---- mean (count via binary search on sorted batch) ----
    pool_div_kernel<<<(N_GRAPHS * HID + 255) / 256, 256, 0, stream>>>(psum, batch, out);
}

// Round 16
// 298.102 us; speedup vs baseline: 1.7431x; 1.0031x over previous
//
#include <hip/hip_runtime.h>

#define N_NODES 50000
#define N_EDGES 600000
#define N_PAD 50048        // N rounded up to 64 (mlp tiles)
#define IN_CH 64
#define HID 128
#define N_GRAPHS 64
#define SCAN_BLOCKS 196   // ceil(N_NODES/256)

typedef __attribute__((ext_vector_type(8))) short bf16x8;
typedef __attribute__((ext_vector_type(4))) float f32x4;

// ---- bf16 helpers (manual, RNE) ----
__device__ __forceinline__ float bf2f(unsigned short u) {
    union { unsigned int i; float f; } v; v.i = ((unsigned int)u) << 16; return v.f;
}
__device__ __forceinline__ unsigned short f2bf(float f) {
    union { float f; unsigned int i; } v; v.f = f;
    unsigned int u = v.i;
    return (unsigned short)((u + 0x7FFFu + ((u >> 16) & 1u)) >> 16);
}

// 8B edge record: x = src(u16) | a0(bf16)<<16 ; y = a1(bf16) | a2(bf16)<<16

// ===========================================================================
// prep kernel (1 dispatch): zero deg+psum, 4 weight transposes, AND x->bf16
// (12.8MB f32 -> 6.4MB bf16 so gather64's random rows halve their working
// set / cross-XCD refetch). Grid = N*IN_CH/256 = 12500 blocks.
// ===========================================================================
__global__ void prep_kernel(const float* __restrict__ x,
                            const float* __restrict__ w1a, const float* __restrict__ w1b,
                            const float* __restrict__ w2a, const float* __restrict__ w2b,
                            unsigned short* __restrict__ xbf,
                            unsigned short* __restrict__ waT1, unsigned short* __restrict__ wbT1,
                            unsigned short* __restrict__ waT2, unsigned short* __restrict__ wbT2,
                            int* __restrict__ deg, float* __restrict__ psum) {
    int i = blockIdx.x * blockDim.x + threadIdx.x;
    if (i < N_NODES * IN_CH) xbf[i] = f2bf(x[i]);
    if (i < N_NODES) deg[i] = 0;
    if (i < N_GRAPHS * HID) psum[i] = 0.f;
    if (i < IN_CH * HID) {               // w1a is [64,128]
        int k = i / HID, n = i % HID;
        waT1[n * IN_CH + k] = f2bf(w1a[i]);
    }
    if (i < HID * HID) {                 // the three [128,128] weights
        int k = i / HID, n = i % HID;
        wbT1[n * HID + k] = f2bf(w1b[i]);
        waT2[n * HID + k] = f2bf(w2a[i]);
        wbT2[n * HID + k] = f2bf(w2b[i]);
    }
}

// ===========================================================================
// CSR build: counting-sort edges by dst into 8B records.
// ===========================================================================
__global__ void hist_kernel(const int* __restrict__ ei, int* __restrict__ deg) {
    int base = (blockIdx.x * blockDim.x + threadIdx.x) * 4;
    if (base < N_EDGES) {   // N_EDGES % 4 == 0, no tail
        int4 d = *(const int4*)(ei + N_EDGES + base);
        atomicAdd(&deg[d.x], 1);
        atomicAdd(&deg[d.y], 1);
        atomicAdd(&deg[d.z], 1);
        atomicAdd(&deg[d.w], 1);
    }
}

__device__ __forceinline__ int block_incl_scan256(int v, int* sm, int t) {
    int val = v;
    sm[t] = val; __syncthreads();
    #pragma unroll
    for (int off = 1; off < 256; off <<= 1) {
        int n = (t >= off) ? sm[t - off] : 0;
        __syncthreads();
        val += n; sm[t] = val; __syncthreads();
    }
    return val;
}

__global__ void scan1_kernel(const int* __restrict__ deg, int* __restrict__ partials) {
    __shared__ int sm[256];
    int t = threadIdx.x;
    int i = blockIdx.x * 256 + t;
    int v = (i < N_NODES) ? deg[i] : 0;
    sm[t] = v; __syncthreads();
    for (int off = 128; off > 0; off >>= 1) {
        if (t < off) sm[t] += sm[t + off];
        __syncthreads();
    }
    if (t == 0) partials[blockIdx.x] = sm[0];
}

// scan3 now folds scan2's 196-partial prefix in (2nd LDS scan) — one fewer
// dispatch (R15: launch slots are a visible cost at this scale).
__global__ void scan3_kernel(const int* __restrict__ deg,
                             const int* __restrict__ partials,
                             int* __restrict__ rowptr,
                             int* __restrict__ cursor) {
    __shared__ int smP[256];
    __shared__ int sm[256];
    int t = threadIdx.x;
    int pv = (t < SCAN_BLOCKS) ? partials[t] : 0;
    block_incl_scan256(pv, smP, t);          // smP[j] = incl prefix of partials
    int base = (blockIdx.x > 0) ? smP[blockIdx.x - 1] : 0;
    int i = blockIdx.x * 256 + t;
    int v = (i < N_NODES) ? deg[i] : 0;
    int incl = block_incl_scan256(v, sm, t);
    int excl = incl - v + base;
    if (i < N_NODES) { rowptr[i] = excl; cursor[i] = excl; }
    if (blockIdx.x == 0 && t == 0) rowptr[N_NODES] = N_EDGES;
}

__global__ void scatter_kernel(const int* __restrict__ ei,
                               const float* __restrict__ ea,
                               int* __restrict__ cursor,
                               uint2* __restrict__ edata) {
    int base = (blockIdx.x * blockDim.x + threadIdx.x) * 4;
    if (base >= N_EDGES) return;   // N_EDGES % 4 == 0, no tail
    int4 s = *(const int4*)(ei + base);
    int4 d = *(const int4*)(ei + N_EDGES + base);
    const float4* ea4 = (const float4*)(ea + (size_t)base * 3);
    float4 A = ea4[0], B = ea4[1], C = ea4[2];
    int p0 = atomicAdd(&cursor[d.x], 1);
    int p1 = atomicAdd(&cursor[d.y], 1);
    int p2 = atomicAdd(&cursor[d.z], 1);
    int p3 = atomicAdd(&cursor[d.w], 1);
    edata[p0] = make_uint2((unsigned)s.x | ((unsigned)f2bf(A.x) << 16),
                           (unsigned)f2bf(A.y) | ((unsigned)f2bf(A.z) << 16));
    edata[p1] = make_uint2((unsigned)s.y | ((unsigned)f2bf(A.w) << 16),
                           (unsigned)f2bf(B.x) | ((unsigned)f2bf(B.y) << 16));
    edata[p2] = make_uint2((unsigned)s.z | ((unsigned)f2bf(B.z) << 16),
                           (unsigned)f2bf(B.w) | ((unsigned)f2bf(C.x) << 16));
    edata[p3] = make_uint2((unsigned)s.w | ((unsigned)f2bf(C.y) << 16),
                           (unsigned)f2bf(C.z) | ((unsigned)f2bf(C.w) << 16));
}

// ===========================================================================
// Layer-1 gather (K=64) — R9/R12-proven structure; now reads bf16 x rows
// (halved working set). Standalone, no LDS.
// ===========================================================================
__global__ void gather64_kernel(const unsigned short* __restrict__ xin,  // bf16 [N,64]
                                const uint2* __restrict__ edata,
                                const int* __restrict__ rowptr,
                                const float* __restrict__ elw,  // [3, 64]
                                const float* __restrict__ elb,  // [64]
                                unsigned short* __restrict__ sg) {  // bf16 [N, 64]
    constexpr int K = IN_CH;
    constexpr int NPB = 8;
    const int node0 = blockIdx.x * NPB;
    const int t = threadIdx.x;  // 0..127
    const int c = t & 63, half = t >> 6;
    const float w0 = elw[c], w1 = elw[K + c], w2 = elw[2 * K + c], eb = elb[c];

    auto term = [&](uint2 e, unsigned short row) -> float {
        float ev = bf2f((unsigned short)(e.x >> 16)) * w0 +
                   bf2f((unsigned short)(e.y & 0xFFFF)) * w1 +
                   bf2f((unsigned short)(e.y >> 16)) * w2 + eb;
        float m = bf2f(row) + ev;
        return m > 0.f ? m : 0.f;
    };

    for (int i = 0; i < NPB; i += 2) {
        int node = node0 + i + half;
        float acc = bf2f(xin[(size_t)node * K + c]);
        int jb = rowptr[node], je = rowptr[node + 1];
        int j = jb;
        for (; j + 8 <= je; j += 8) {
            uint2 e0 = edata[j],     e1 = edata[j + 1], e2 = edata[j + 2], e3 = edata[j + 3];
            uint2 e4 = edata[j + 4], e5 = edata[j + 5], e6 = edata[j + 6], e7 = edata[j + 7];
            unsigned short r0 = xin[(size_t)(e0.x & 0xFFFF) * K + c];
            unsigned short r1 = xin[(size_t)(e1.x & 0xFFFF) * K + c];
            unsigned short r2 = xin[(size_t)(e2.x & 0xFFFF) * K + c];
            unsigned short r3 = xin[(size_t)(e3.x & 0xFFFF) * K + c];
            unsigned short r4 = xin[(size_t)(e4.x & 0xFFFF) * K + c];
            unsigned short r5 = xin[(size_t)(e5.x & 0xFFFF) * K + c];
            unsigned short r6 = xin[(size_t)(e6.x & 0xFFFF) * K + c];
            unsigned short r7 = xin[(size_t)(e7.x & 0xFFFF) * K + c];
            acc += term(e0, r0) + term(e1, r1) + term(e2, r2) + term(e3, r3)
                 + term(e4, r4) + term(e5, r5) + term(e6, r6) + term(e7, r7);
        }
        for (; j + 4 <= je; j += 4) {
            uint2 e0 = edata[j], e1 = edata[j + 1], e2 = edata[j + 2], e3 = edata[j + 3];
            unsigned short r0 = xin[(size_t)(e0.x & 0xFFFF) * K + c];
            unsigned short r1 = xin[(size_t)(e1.x & 0xFFFF) * K + c];
            unsigned short r2 = xin[(size_t)(e2.x & 0xFFFF) * K + c];
            unsigned short r3 = xin[(size_t)(e3.x & 0xFFFF) * K + c];
            acc += term(e0, r0) + term(e1, r1) + term(e2, r2) + term(e3, r3);
        }
        for (; j < je; j++) {
            uint2 e0 = edata[j];
            acc += term(e0, xin[(size_t)(e0.x & 0xFFFF) * K + c]);
        }
        sg[(size_t)node * K + c] = f2bf(acc);
    }
}

// ===========================================================================
// Layer-2 gather (K=128, bf16), packed u32 lanes, paired-lockstep — R15-proven.
// ===========================================================================
__global__ void gather128_kernel(const unsigned short* __restrict__ xin,  // bf16 [N,128]
                                 const uint2* __restrict__ edata,
                                 const int* __restrict__ rowptr,
                                 const float* __restrict__ elw,  // [3, 128]
                                 const float* __restrict__ elb,  // [128]
                                 unsigned short* __restrict__ sg) {  // bf16 [N, 128]
    const int t = threadIdx.x;
    const int w = t >> 6, l = t & 63;
    const unsigned* x32 = (const unsigned*)xin;       // row = 64 uints
    unsigned* sg32 = (unsigned*)sg;
    const int c0 = 2 * l;
    const float w00 = elw[c0],           w01 = elw[c0 + 1];
    const float w10 = elw[HID + c0],     w11 = elw[HID + c0 + 1];
    const float w20 = elw[2 * HID + c0], w21 = elw[2 * HID + c0 + 1];
    const float eb0 = elb[c0],           eb1 = elb[c0 + 1];
    const int node0 = (blockIdx.x * 4 + w) * 4;

    for (int ni = 0; ni < 4; ni += 2) {
        int nA = node0 + ni, nB = node0 + ni + 1;
        unsigned svA = x32[(size_t)nA * 64 + l];
        unsigned svB = x32[(size_t)nB * 64 + l];
        float a0 = bf2f((unsigned short)(svA & 0xFFFF));
        float a1 = bf2f((unsigned short)(svA >> 16));
        float b0 = bf2f((unsigned short)(svB & 0xFFFF));
        float b1 = bf2f((unsigned short)(svB >> 16));

        auto term2 = [&](uint2 e, unsigned r, float& p0, float& p1) {
            float A0 = bf2f((unsigned short)(e.x >> 16));
            float A1 = bf2f((unsigned short)(e.y & 0xFFFF));
            float A2 = bf2f((unsigned short)(e.y >> 16));
            float ev0 = A0 * w00 + A1 * w10 + A2 * w20 + eb0;
            float ev1 = A0 * w01 + A1 * w11 + A2 * w21 + eb1;
            float m0 = bf2f((unsigned short)(r & 0xFFFF)) + ev0;
            float m1 = bf2f((unsigned short)(r >> 16)) + ev1;
            p0 += m0 > 0.f ? m0 : 0.f;
            p1 += m1 > 0.f ? m1 : 0.f;
        };

        int ja = rowptr[nA], jaE = rowptr[nA + 1];
        int jb = rowptr[nB], jbE = rowptr[nB + 1];
        while (ja + 4 <= jaE && jb + 4 <= jbE) {
            uint2 eA0 = edata[ja],     eA1 = edata[ja + 1], eA2 = edata[ja + 2], eA3 = edata[ja + 3];
            uint2 eB0 = edata[jb],     eB1 = edata[jb + 1], eB2 = edata[jb + 2], eB3 = edata[jb + 3];
            unsigned rA0 = x32[(size_t)(eA0.x & 0xFFFF) * 64 + l];
            unsigned rA1 = x32[(size_t)(eA1.x & 0xFFFF) * 64 + l];
            unsigned rA2 = x32[(size_t)(eA2.x & 0xFFFF) * 64 + l];
            unsigned rA3 = x32[(size_t)(eA3.x & 0xFFFF) * 64 + l];
            unsigned rB0 = x32[(size_t)(eB0.x & 0xFFFF) * 64 + l];
            unsigned rB1 = x32[(size_t)(eB1.x & 0xFFFF) * 64 + l];
            unsigned rB2 = x32[(size_t)(eB2.x & 0xFFFF) * 64 + l];
            unsigned rB3 = x32[(size_t)(eB3.x & 0xFFFF) * 64 + l];
            term2(eA0, rA0, a0, a1); term2(eA1, rA1, a0, a1);
            term2(eA2, rA2, a0, a1); term2(eA3, rA3, a0, a1);
            term2(eB0, rB0, b0, b1); term2(eB1, rB1, b0, b1);
            term2(eB2, rB2, b0, b1); term2(eB3, rB3, b0, b1);
            ja += 4; jb += 4;
        }
        for (; ja + 4 <= jaE; ja += 4) {
            uint2 e0 = edata[ja], e1 = edata[ja + 1], e2 = edata[ja + 2], e3 = edata[ja + 3];
            unsigned r0 = x32[(size_t)(e0.x & 0xFFFF) * 64 + l];
            unsigned r1 = x32[(size_t)(e1.x & 0xFFFF) * 64 + l];
            unsigned r2 = x32[(size_t)(e2.x & 0xFFFF) * 64 + l];
            unsigned r3 = x32[(size_t)(e3.x & 0xFFFF) * 64 + l];
            term2(e0, r0, a0, a1); term2(e1, r1, a0, a1);
            term2(e2, r2, a0, a1); term2(e3, r3, a0, a1);
        }
        for (; ja < jaE; ja++) {
            uint2 e0 = edata[ja];
            term2(e0, x32[(size_t)(e0.x & 0xFFFF) * 64 + l], a0, a1);
        }
        for (; jb + 4 <= jbE; jb += 4) {
            uint2 e0 = edata[jb], e1 = edata[jb + 1], e2 = edata[jb + 2], e3 = edata[jb + 3];
            unsigned r0 = x32[(size_t)(e0.x & 0xFFFF) * 64 + l];
            unsigned r1 = x32[(size_t)(e1.x & 0xFFFF) * 64 + l];
            unsigned r2 = x32[(size_t)(e2.x & 0xFFFF) * 64 + l];
            unsigned r3 = x32[(size_t)(e3.x & 0xFFFF) * 64 + l];
            term2(e0, r0, b0, b1); term2(e1, r1, b0, b1);
            term2(e2, r2, b0, b1); term2(e3, r3, b0, b1);
        }
        for (; jb < jbE; jb++) {
            uint2 e0 = edata[jb];
            term2(e0, x32[(size_t)(e0.x & 0xFFFF) * 64 + l], b0, b1);
        }
        sg32[(size_t)nA * 64 + l] = (unsigned)f2bf(a0) | ((unsigned)f2bf(a1) << 16);
        sg32[(size_t)nB * 64 + l] = (unsigned)f2bf(b0) | ((unsigned)f2bf(b1) << 16);
    }
}

// ===========================================================================
// Standalone MFMA MLP — R12-proven (MFMA body + LDS-staged epilogue).
// ===========================================================================
template <int K, bool POOL>
__global__ __launch_bounds__(256)
void mlp_mfma_kernel(const unsigned short* __restrict__ sg,   // bf16 [N_PAD, K]
                     const unsigned short* __restrict__ waT,  // bf16 [HID, K]
                     const float* __restrict__ ba,
                     const unsigned short* __restrict__ wbT,  // bf16 [HID, HID]
                     const float* __restrict__ bb,
                     void* __restrict__ outv,                 // bf16 h or f32 psum
                     const int* __restrict__ batch) {
    constexpr int HSTR = 136;      // shorts
    constexpr int OSTR = HID + 4;  // f32
    __shared__ __align__(16) unsigned short sHid[4][16 * HSTR];  // 17.4 KB
    __shared__ __align__(16) float sOut[64 * OSTR];              // 33.8 KB
    const int t = threadIdx.x;
    const int w = t >> 6, l = t & 63;
    const int i16 = l & 15, q = l >> 4;
    const int blk0 = blockIdx.x * 64;
    const int row0 = blk0 + w * 16;   // this wave's 16 rows

    // ---- layer A: [16 x K] @ waT -> relu -> own LDS buffer ----
    bf16x8 aA[K / 32];
    #pragma unroll
    for (int s = 0; s < K / 32; s++)
        aA[s] = *(const bf16x8*)&sg[(size_t)(row0 + i16) * K + s * 32 + q * 8];
    unsigned short* myHid = sHid[w];
    #pragma unroll
    for (int ct = 0; ct < 8; ct++) {
        int col = ct * 16 + i16;
        float bv = ba[col];
        f32x4 acc = (f32x4){bv, bv, bv, bv};
        #pragma unroll
        for (int s = 0; s < K / 32; s++) {
            bf16x8 b = *(const bf16x8*)&waT[(size_t)col * K + s * 32 + q * 8];
            acc = __builtin_amdgcn_mfma_f32_16x16x32_bf16(aA[s], b, acc, 0, 0, 0);
        }
        #pragma unroll
        for (int r = 0; r < 4; r++) {
            float v = acc[r] > 0.f ? acc[r] : 0.f;
            myHid[(q * 4 + r) * HSTR + col] = f2bf(v);
        }
    }
    __syncthreads();

    // ---- layer B: [16 x 128] @ wbT -> relu -> sOut (f32 LDS) ----
    bf16x8 aB[4];
    #pragma unroll
    for (int s = 0; s < 4; s++)
        aB[s] = *(const bf16x8*)&myHid[i16 * HSTR + s * 32 + q * 8];
    #pragma unroll
    for (int ct = 0; ct < 8; ct++) {
        int col = ct * 16 + i16;
        float bv = bb[col];
        f32x4 acc = (f32x4){bv, bv, bv, bv};
        #pragma unroll
        for (int s = 0; s < 4; s++) {
            bf16x8 b = *(const bf16x8*)&wbT[(size_t)col * HID + s * 32 + q * 8];
            acc = __builtin_amdgcn_mfma_f32_16x16x32_bf16(aB[s], b, acc, 0, 0, 0);
        }
        #pragma unroll
        for (int r = 0; r < 4; r++) {
            float v = acc[r] > 0.f ? acc[r] : 0.f;
            sOut[(w * 16 + q * 4 + r) * OSTR + col] = v;
        }
    }
    __syncthreads();

    // ---- epilogue (R12-proven) ----
    if (POOL) {
        if (t < HID) {
            float* psum = (float*)outv;
            float acc = 0.f;
            int curg = batch[blk0];
            for (int row = 0; row < 64; row++) {
                int node = blk0 + row;
                if (node >= N_NODES) break;
                int g = batch[node];
                if (g != curg) {
                    atomicAdd(&psum[curg * HID + t], acc);
                    acc = 0.f; curg = g;
                }
                acc += sOut[row * OSTR + t];
            }
            atomicAdd(&psum[curg * HID + t], acc);
        }
    } else {
        unsigned short* hout = (unsigned short*)outv;
        for (int idx = t; idx < 64 * 16; idx += 256) {
            int row = idx >> 4, ch = idx & 15;   // ch = 16B chunk (8 bf16)
            int node = blk0 + row;
            if (node < N_NODES) {
                float4 f0 = *(const float4*)&sOut[row * OSTR + ch * 8];
                float4 f1 = *(const float4*)&sOut[row * OSTR + ch * 8 + 4];
                uint4 u;
                u.x = (unsigned)f2bf(f0.x) | ((unsigned)f2bf(f0.y) << 16);
                u.y = (unsigned)f2bf(f0.z) | ((unsigned)f2bf(f0.w) << 16);
                u.z = (unsigned)f2bf(f1.x) | ((unsigned)f2bf(f1.y) << 16);
                u.w = (unsigned)f2bf(f1.z) | ((unsigned)f2bf(f1.w) << 16);
                *(uint4*)&hout[(size_t)node * HID + ch * 8] = u;
            }
        }
    }
}

// ---------------------------------------------------------------------------
// Pool mean: batch is SORTED -> count[g] by binary search (wave-uniform).
// ---------------------------------------------------------------------------
__global__ void pool_div_kernel(const float* __restrict__ sums,
                                const int* __restrict__ batch,
                                float* __restrict__ out) {
    int i = blockIdx.x * blockDim.x + threadIdx.x;
    if (i >= N_GRAPHS * HID) return;
    int g = i / HID;
    int lo = 0, hi = N_NODES;
    while (lo < hi) { int mid = (lo + hi) >> 1; if (batch[mid] < g) lo = mid + 1; else hi = mid; }
    int start = lo;
    lo = 0; hi = N_NODES;
    while (lo < hi) { int mid = (lo + hi) >> 1; if (batch[mid] <= g) lo = mid + 1; else hi = mid; }
    float c = (float)(lo - start);
    out[i] = sums[i] / (c > 1.0f ? c : 1.0f);
}

extern "C" void kernel_launch(void* const* d_in, const int* in_sizes, int n_in,
                              void* d_out, int out_size, void* d_ws, size_t ws_size,
                              hipStream_t stream) {
    const float* x    = (const float*)d_in[0];
    const int*   ei   = (const int*)d_in[1];
    const float* ea   = (const float*)d_in[2];
    const int*   batch= (const int*)d_in[3];
    const float* el1w = (const float*)d_in[4];
    const float* el1b = (const float*)d_in[5];
    const float* w1a  = (const float*)d_in[6];
    const float* b1a  = (const float*)d_in[7];
    const float* w1b  = (const float*)d_in[8];
    const float* b1b  = (const float*)d_in[9];
    const float* el2w = (const float*)d_in[10];
    const float* el2b = (const float*)d_in[11];
    const float* w2a  = (const float*)d_in[12];
    const float* b2a  = (const float*)d_in[13];
    const float* w2b  = (const float*)d_in[14];
    const float* b2b  = (const float*)d_in[15];
    float* out = (float*)d_out;

    // workspace layout (16B-aligned sections)
    uint2* edata    = (uint2*)d_ws;                     // [E] 8B records      4.8 MB
    float* psum     = (float*)(edata + N_EDGES);        // [G*HID] 8192 f32
    int*   deg      = (int*)(psum + N_GRAPHS * HID);    // [N]
    int*   cursor   = deg + N_NODES;                    // [N]
    int*   rowptr   = cursor + N_NODES;                 // [N+1]
    int*   partials = rowptr + N_NODES + 1;             // [256]
    // ints so far: 8192+50000+50000+50001+256 = 158449; pad to 158452 (16B mult)
    unsigned short* hbf  = (unsigned short*)((char*)psum + (size_t)158452 * 4);  // bf16 [N,HID]
    unsigned short* sgbuf= hbf + (size_t)N_NODES * HID;  // bf16 [N_PAD, 128] (layer1 uses stride 64)
    unsigned short* waT1 = sgbuf + (size_t)N_PAD * HID;  // bf16 [128, 64]
    unsigned short* wbT1 = waT1 + HID * IN_CH;           // bf16 [128, 128]
    unsigned short* waT2 = wbT1 + HID * HID;             // bf16 [128, 128]
    unsigned short* wbT2 = waT2 + HID * HID;             // bf16 [128, 128]
    unsigned short* xbf  = wbT2 + HID * HID;             // bf16 [N, 64]

    // ---- prep (1 dispatch): zero deg+psum, transpose weights, x->bf16 ----
    prep_kernel<<<(N_NODES * IN_CH) / 256, 256, 0, stream>>>(
        x, w1a, w1b, w2a, w2b, xbf, waT1, wbT1, waT2, wbT2, deg, psum);
    // ---- CSR build (scan2 folded into scan3) ----
    hist_kernel<<<(N_EDGES / 4 + 255) / 256, 256, 0, stream>>>(ei, deg);
    scan1_kernel<<<SCAN_BLOCKS, 256, 0, stream>>>(deg, partials);
    scan3_kernel<<<SCAN_BLOCKS, 256, 0, stream>>>(deg, partials, rowptr, cursor);
    scatter_kernel<<<(N_EDGES / 4 + 255) / 256, 256, 0, stream>>>(ei, ea, cursor, edata);

    // ---- layer 1: bf16 gather -> sg ; MFMA MLP -> hbf (bf16) ----
    gather64_kernel<<<N_NODES / 8, 128, 0, stream>>>(
        xbf, edata, rowptr, el1w, el1b, sgbuf);
    mlp_mfma_kernel<IN_CH, false><<<N_PAD / 64, 256, 0, stream>>>(
        sgbuf, waT1, b1a, wbT1, b1b, hbf, nullptr);

    // ---- layer 2: paired-lockstep bf16 gather ; MFMA MLP + LDS pool ----
    gather128_kernel<<<N_NODES / 16, 256, 0, stream>>>(
        hbf, edata, rowptr, el2w, el2b, sgbuf);
    mlp_mfma_kernel<HID, true><<<N_PAD / 64, 256, 0, stream>>>(
        sgbuf, waT2, b2a, wbT2, b2b, psum, batch);

    // ---- mean (count via binary search on sorted batch) ----
    pool_div_kernel<<<(N_GRAPHS * HID + 255) / 256, 256, 0, stream>>>(psum, batch, out);
}